// Round 1
// baseline (419.955 us; speedup 1.0000x reference)
//
#include <hip/hip_runtime.h>
#include <hip/hip_bf16.h>

#define NN 100000
#define NE 625000
#define D  128

static constexpr size_t AL(size_t x){ return (x + 511) & ~(size_t)511; }
static constexpr size_t OFF_DEG    = 0;                          // int[NN]
static constexpr size_t OFF_ROWOFS = AL(OFF_DEG    + (size_t)NN*4); // int[NN]
static constexpr size_t OFF_CURSOR = AL(OFF_ROWOFS + (size_t)NN*4); // int[NN]
static constexpr size_t OFF_DINV   = AL(OFF_CURSOR + (size_t)NN*4); // float[NN]
static constexpr size_t OFF_FLAG   = AL(OFF_DINV   + (size_t)NN*4); // int[16]
static constexpr size_t OFF_ELIST  = AL(OFF_FLAG   + 64);           // int[NE]
static constexpr size_t OFF_HBF    = AL(OFF_ELIST  + (size_t)NE*4); // bf16[NN*D] as uint32[NN*D/2]

// ---------- helpers ----------
__device__ inline unsigned f2bf2(float a, float b){
    // round-to-nearest-even f32 -> bf16, pack two into a uint32 (a=low, b=high)
    unsigned ua = __float_as_uint(a), ub = __float_as_uint(b);
    ua += 0x7fffu + ((ua >> 16) & 1u);
    ub += 0x7fffu + ((ub >> 16) & 1u);
    return (ua >> 16) | (ub & 0xffff0000u);
}
__device__ inline float2 bf2f2(unsigned u){
    float2 r;
    r.x = __uint_as_float(u << 16);
    r.y = __uint_as_float(u & 0xffff0000u);
    return r;
}
__device__ inline int get_idx(const void* p, long long i, int is64){
    return is64 ? (int)((const long long*)p)[i] : ((const int*)p)[i];
}

// ---------- kernels ----------
// Detect whether edge_index buffer holds int64 (odd 32-bit words all zero) or int32.
__global__ void detect_kernel(const void* eidx, int* flag){
    if(blockIdx.x == 0 && threadIdx.x == 0){
        const int* p = (const int*)eidx;
        int allz = 1;
        for(int i = 1; i < 64; i += 2) allz &= (p[i] == 0);
        *flag = allz;  // 1 => int64 layout
    }
}

__global__ void count_kernel(const void* eidx, const int* __restrict__ flag,
                             int* __restrict__ deg){
    const int is64 = *flag;
    for(int e = blockIdx.x * blockDim.x + threadIdx.x; e < NE;
        e += gridDim.x * blockDim.x){
        int d = get_idx(eidx, (long long)NE + e, is64);
        atomicAdd(&deg[d], 1);
    }
}

// Single-block exclusive scan of deg -> rowofs; also dinv = rsqrt(deg+1).
__global__ __launch_bounds__(1024) void scan_kernel(const int* __restrict__ deg,
                                                    int* __restrict__ rowofs,
                                                    float* __restrict__ dinv){
    __shared__ int sums[1024];
    const int t = threadIdx.x;
    const int C = (NN + 1023) / 1024;          // 98
    const int lo = t * C;
    const int hi = min(lo + C, NN);
    int s = 0;
    for(int i = lo; i < hi; i++) s += deg[i];
    sums[t] = s;
    __syncthreads();
    for(int off = 1; off < 1024; off <<= 1){
        int v = sums[t];
        int u = (t >= off) ? sums[t - off] : 0;
        __syncthreads();
        sums[t] = v + u;
        __syncthreads();
    }
    int run = (t == 0) ? 0 : sums[t - 1];
    for(int i = lo; i < hi; i++){
        rowofs[i] = run;
        int dg = deg[i];
        run += dg;
        dinv[i] = rsqrtf((float)(dg + 1));
    }
}

// Scatter only unmasked->unmasked edges into CSR buckets; cursor = effective length.
__global__ void scatter_kernel(const void* eidx, const int* __restrict__ flag,
                               const int* __restrict__ mask,
                               const int* __restrict__ rowofs,
                               int* __restrict__ cursor, int* __restrict__ elist){
    const int is64 = *flag;
    for(int e = blockIdx.x * blockDim.x + threadIdx.x; e < NE;
        e += gridDim.x * blockDim.x){
        int s = get_idx(eidx, e, is64);
        int d = get_idx(eidx, (long long)NE + e, is64);
        if(mask[s] && mask[d]){
            int p = atomicAdd(&cursor[d], 1);
            elist[rowofs[d] + p] = s;
        }
    }
}

// h = (x .* mask) @ W, stored bf16. 16 rows/block, 4 rows/wave.
__global__ __launch_bounds__(256) void gemm_kernel(const float* __restrict__ x,
                                                   const float* __restrict__ W,
                                                   const int* __restrict__ mask,
                                                   unsigned* __restrict__ hbf){
    __shared__ float Wl[D * D];     // 64 KB
    __shared__ float xs[16][D];     //  8 KB
    const int t = threadIdx.x;
    {
        const float4* Ws = (const float4*)W;
        float4* Wd = (float4*)Wl;
        for(int i = t; i < D * D / 4; i += 256) Wd[i] = Ws[i];
    }
    const int r0 = blockIdx.x * 16;          // NN % 16 == 0 -> no tail
    for(int i = t; i < 16 * (D / 2); i += 256){
        int row = i >> 6, c2 = i & 63;
        int r = r0 + row;
        float mv = (float)mask[r];
        float2 v = *(const float2*)&x[(size_t)r * D + c2 * 2];
        xs[row][c2 * 2]     = v.x * mv;
        xs[row][c2 * 2 + 1] = v.y * mv;
    }
    __syncthreads();

    const int wave = t >> 6, lane = t & 63;
    float2 acc[4];
#pragma unroll
    for(int j = 0; j < 4; j++) acc[j] = make_float2(0.f, 0.f);

    const float* xr0 = xs[wave * 4 + 0];
    const float* xr1 = xs[wave * 4 + 1];
    const float* xr2 = xs[wave * 4 + 2];
    const float* xr3 = xs[wave * 4 + 3];

#pragma unroll 4
    for(int k = 0; k < D; k += 4){
        float4 a0 = *(const float4*)&xr0[k];
        float4 a1 = *(const float4*)&xr1[k];
        float4 a2 = *(const float4*)&xr2[k];
        float4 a3 = *(const float4*)&xr3[k];
        float2 w0 = *(const float2*)&Wl[(k + 0) * D + 2 * lane];
        float2 w1 = *(const float2*)&Wl[(k + 1) * D + 2 * lane];
        float2 w2 = *(const float2*)&Wl[(k + 2) * D + 2 * lane];
        float2 w3 = *(const float2*)&Wl[(k + 3) * D + 2 * lane];
        acc[0].x += a0.x * w0.x + a0.y * w1.x + a0.z * w2.x + a0.w * w3.x;
        acc[0].y += a0.x * w0.y + a0.y * w1.y + a0.z * w2.y + a0.w * w3.y;
        acc[1].x += a1.x * w0.x + a1.y * w1.x + a1.z * w2.x + a1.w * w3.x;
        acc[1].y += a1.x * w0.y + a1.y * w1.y + a1.z * w2.y + a1.w * w3.y;
        acc[2].x += a2.x * w0.x + a2.y * w1.x + a2.z * w2.x + a2.w * w3.x;
        acc[2].y += a2.x * w0.y + a2.y * w1.y + a2.z * w2.y + a2.w * w3.y;
        acc[3].x += a3.x * w0.x + a3.y * w1.x + a3.z * w2.x + a3.w * w3.x;
        acc[3].y += a3.x * w0.y + a3.y * w1.y + a3.z * w2.y + a3.w * w3.y;
    }
#pragma unroll
    for(int j = 0; j < 4; j++){
        int r = r0 + wave * 4 + j;
        hbf[(size_t)r * (D / 2) + lane] = f2bf2(acc[j].x, acc[j].y);
    }
}

// out[n] = m[n] * ( dinv[n]*(dinv[n]*h[n] + sum_e dinv[s]*h[s]) + bias )
// One wave per node; lane owns 2 output dims.
__global__ __launch_bounds__(256) void agg_kernel(const unsigned* __restrict__ hbf,
                                                  const float* __restrict__ dinv,
                                                  const int* __restrict__ rowofs,
                                                  const int* __restrict__ cursor,
                                                  const int* __restrict__ elist,
                                                  const int* __restrict__ mask,
                                                  const float* __restrict__ bias,
                                                  float* __restrict__ out){
    const int t = threadIdx.x;
    const int wave = t >> 6, lane = t & 63;
    const int n = blockIdx.x * 4 + wave;     // NN % 4 == 0
    float2* outp = (float2*)&out[(size_t)n * D + 2 * lane];
    if(!mask[n]){
        *outp = make_float2(0.f, 0.f);
        return;
    }
    const float dn = dinv[n];
    float2 hs = bf2f2(hbf[(size_t)n * (D / 2) + lane]);   // self-loop
    float2 acc = make_float2(dn * hs.x, dn * hs.y);
    const int base = rowofs[n];
    const int len  = cursor[n];
    for(int j = 0; j < len; j++){
        int s = elist[base + j];
        float ds = dinv[s];
        float2 hv = bf2f2(hbf[(size_t)s * (D / 2) + lane]);
        acc.x += ds * hv.x;
        acc.y += ds * hv.y;
    }
    float2 b = *(const float2*)&bias[2 * lane];
    outp->x = dn * acc.x + b.x;
    outp->y = dn * acc.y + b.y;
}

extern "C" void kernel_launch(void* const* d_in, const int* in_sizes, int n_in,
                              void* d_out, int out_size, void* d_ws, size_t ws_size,
                              hipStream_t stream){
    const float* x    = (const float*)d_in[0];
    const float* W    = (const float*)d_in[1];
    const float* bias = (const float*)d_in[2];
    const void*  eidx = d_in[3];
    const int*   mask = (const int*)d_in[4];
    float* out = (float*)d_out;

    char* ws = (char*)d_ws;
    int*      deg    = (int*)(ws + OFF_DEG);
    int*      rowofs = (int*)(ws + OFF_ROWOFS);
    int*      cursor = (int*)(ws + OFF_CURSOR);
    float*    dinv   = (float*)(ws + OFF_DINV);
    int*      flag   = (int*)(ws + OFF_FLAG);
    int*      elist  = (int*)(ws + OFF_ELIST);
    unsigned* hbf    = (unsigned*)(ws + OFF_HBF);

    hipMemsetAsync(deg,    0, (size_t)NN * 4, stream);
    hipMemsetAsync(cursor, 0, (size_t)NN * 4, stream);
    detect_kernel <<<1,    64,  0, stream>>>(eidx, flag);
    count_kernel  <<<1024, 256, 0, stream>>>(eidx, flag, deg);
    scan_kernel   <<<1,    1024,0, stream>>>(deg, rowofs, dinv);
    scatter_kernel<<<1024, 256, 0, stream>>>(eidx, flag, mask, rowofs, cursor, elist);
    gemm_kernel   <<<NN/16,256, 0, stream>>>(x, W, mask, hbf);
    agg_kernel    <<<NN/4, 256, 0, stream>>>(hbf, dinv, rowofs, cursor, elist, mask, bias, out);
}

// Round 2
// 206.055 us; speedup vs baseline: 2.0381x; 2.0381x over previous
//
#include <hip/hip_runtime.h>
#include <hip/hip_bf16.h>

#define NN 100000
#define NE 625000
#define D  128
#define SCAN_BLOCKS 98   // 98*1024 >= NN

static constexpr size_t AL(size_t x){ return (x + 511) & ~(size_t)511; }
static constexpr size_t OFF_DEG    = 0;                          // int[NN]
static constexpr size_t OFF_ROWOFS = AL(OFF_DEG    + (size_t)NN*4); // int[NN]
static constexpr size_t OFF_CURSOR = AL(OFF_ROWOFS + (size_t)NN*4); // int[NN]
static constexpr size_t OFF_DINV   = AL(OFF_CURSOR + (size_t)NN*4); // float[NN]
static constexpr size_t OFF_FLAG   = AL(OFF_DINV   + (size_t)NN*4); // int[16]
static constexpr size_t OFF_PART   = AL(OFF_FLAG   + 64);           // int[128] partials+blockofs
static constexpr size_t OFF_ELIST  = AL(OFF_PART   + 512);          // int[NE]
static constexpr size_t OFF_HBF    = AL(OFF_ELIST  + (size_t)NE*4); // bf16[NN*D] as uint32[NN*D/2]

// ---------- helpers ----------
__device__ inline unsigned f2bf2(float a, float b){
    // round-to-nearest-even f32 -> bf16, pack two into a uint32 (a=low, b=high)
    unsigned ua = __float_as_uint(a), ub = __float_as_uint(b);
    ua += 0x7fffu + ((ua >> 16) & 1u);
    ub += 0x7fffu + ((ub >> 16) & 1u);
    return (ua >> 16) | (ub & 0xffff0000u);
}
__device__ inline float2 bf2f2(unsigned u){
    float2 r;
    r.x = __uint_as_float(u << 16);
    r.y = __uint_as_float(u & 0xffff0000u);
    return r;
}
__device__ inline int get_idx(const void* p, long long i, int is64){
    return is64 ? (int)((const long long*)p)[i] : ((const int*)p)[i];
}

// ---------- kernels ----------
// Detect whether edge_index buffer holds int64 (odd 32-bit words all zero) or int32.
__global__ void detect_kernel(const void* eidx, int* flag){
    if(blockIdx.x == 0 && threadIdx.x == 0){
        const int* p = (const int*)eidx;
        int allz = 1;
        for(int i = 1; i < 64; i += 2) allz &= (p[i] == 0);
        *flag = allz;  // 1 => int64 layout
    }
}

__global__ void count_kernel(const void* eidx, const int* __restrict__ flag,
                             int* __restrict__ deg){
    const int is64 = *flag;
    for(int e = blockIdx.x * blockDim.x + threadIdx.x; e < NE;
        e += gridDim.x * blockDim.x){
        int d = get_idx(eidx, (long long)NE + e, is64);
        atomicAdd(&deg[d], 1);
    }
}

// Hierarchical exclusive scan of deg -> rowofs (3 passes), fused dinv in pass 1.
__global__ __launch_bounds__(1024) void scan1_kernel(const int* __restrict__ deg,
                                                     int* __restrict__ rowofs,
                                                     int* __restrict__ partials,
                                                     float* __restrict__ dinv){
    __shared__ int s[1024];
    const int tid = threadIdx.x;
    const int i = blockIdx.x * 1024 + tid;
    const int v = (i < NN) ? deg[i] : 0;
    s[tid] = v;
    __syncthreads();
    for(int off = 1; off < 1024; off <<= 1){
        int u = (tid >= off) ? s[tid - off] : 0;
        __syncthreads();
        s[tid] += u;
        __syncthreads();
    }
    if(i < NN){
        rowofs[i] = s[tid] - v;                 // block-local exclusive
        dinv[i]   = rsqrtf((float)(v + 1));
    }
    if(tid == 1023) partials[blockIdx.x] = s[tid];
}

__global__ __launch_bounds__(128) void scan2_kernel(int* __restrict__ partials){
    __shared__ int s[128];
    const int tid = threadIdx.x;
    const int v = (tid < SCAN_BLOCKS) ? partials[tid] : 0;
    s[tid] = v;
    __syncthreads();
    for(int off = 1; off < 128; off <<= 1){
        int u = (tid >= off) ? s[tid - off] : 0;
        __syncthreads();
        s[tid] += u;
        __syncthreads();
    }
    if(tid < SCAN_BLOCKS) partials[tid] = s[tid] - v;   // exclusive block offsets (in place)
}

__global__ __launch_bounds__(1024) void scan3_kernel(int* __restrict__ rowofs,
                                                     const int* __restrict__ partials){
    const int i = blockIdx.x * 1024 + threadIdx.x;
    if(i < NN) rowofs[i] += partials[blockIdx.x];
}

// Scatter only unmasked->unmasked edges into CSR buckets; cursor = effective length.
__global__ void scatter_kernel(const void* eidx, const int* __restrict__ flag,
                               const int* __restrict__ mask,
                               const int* __restrict__ rowofs,
                               int* __restrict__ cursor, int* __restrict__ elist){
    const int is64 = *flag;
    for(int e = blockIdx.x * blockDim.x + threadIdx.x; e < NE;
        e += gridDim.x * blockDim.x){
        int s = get_idx(eidx, e, is64);
        int d = get_idx(eidx, (long long)NE + e, is64);
        if(mask[s] && mask[d]){
            int p = atomicAdd(&cursor[d], 1);
            elist[rowofs[d] + p] = s;
        }
    }
}

// h = (x .* mask) @ W, stored bf16. 16 rows/block, 4 rows/wave.
__global__ __launch_bounds__(256) void gemm_kernel(const float* __restrict__ x,
                                                   const float* __restrict__ W,
                                                   const int* __restrict__ mask,
                                                   unsigned* __restrict__ hbf){
    __shared__ float Wl[D * D];     // 64 KB
    __shared__ float xs[16][D];     //  8 KB
    const int t = threadIdx.x;
    {
        const float4* Ws = (const float4*)W;
        float4* Wd = (float4*)Wl;
        for(int i = t; i < D * D / 4; i += 256) Wd[i] = Ws[i];
    }
    const int r0 = blockIdx.x * 16;          // NN % 16 == 0 -> no tail
    for(int i = t; i < 16 * (D / 2); i += 256){
        int row = i >> 6, c2 = i & 63;
        int r = r0 + row;
        float mv = (float)mask[r];
        float2 v = *(const float2*)&x[(size_t)r * D + c2 * 2];
        xs[row][c2 * 2]     = v.x * mv;
        xs[row][c2 * 2 + 1] = v.y * mv;
    }
    __syncthreads();

    const int wave = t >> 6, lane = t & 63;
    float2 acc[4];
#pragma unroll
    for(int j = 0; j < 4; j++) acc[j] = make_float2(0.f, 0.f);

    const float* xr0 = xs[wave * 4 + 0];
    const float* xr1 = xs[wave * 4 + 1];
    const float* xr2 = xs[wave * 4 + 2];
    const float* xr3 = xs[wave * 4 + 3];

#pragma unroll 4
    for(int k = 0; k < D; k += 4){
        float4 a0 = *(const float4*)&xr0[k];
        float4 a1 = *(const float4*)&xr1[k];
        float4 a2 = *(const float4*)&xr2[k];
        float4 a3 = *(const float4*)&xr3[k];
        float2 w0 = *(const float2*)&Wl[(k + 0) * D + 2 * lane];
        float2 w1 = *(const float2*)&Wl[(k + 1) * D + 2 * lane];
        float2 w2 = *(const float2*)&Wl[(k + 2) * D + 2 * lane];
        float2 w3 = *(const float2*)&Wl[(k + 3) * D + 2 * lane];
        acc[0].x += a0.x * w0.x + a0.y * w1.x + a0.z * w2.x + a0.w * w3.x;
        acc[0].y += a0.x * w0.y + a0.y * w1.y + a0.z * w2.y + a0.w * w3.y;
        acc[1].x += a1.x * w0.x + a1.y * w1.x + a1.z * w2.x + a1.w * w3.x;
        acc[1].y += a1.x * w0.y + a1.y * w1.y + a1.z * w2.y + a1.w * w3.y;
        acc[2].x += a2.x * w0.x + a2.y * w1.x + a2.z * w2.x + a2.w * w3.x;
        acc[2].y += a2.x * w0.y + a2.y * w1.y + a2.z * w2.y + a2.w * w3.y;
        acc[3].x += a3.x * w0.x + a3.y * w1.x + a3.z * w2.x + a3.w * w3.x;
        acc[3].y += a3.x * w0.y + a3.y * w1.y + a3.z * w2.y + a3.w * w3.y;
    }
#pragma unroll
    for(int j = 0; j < 4; j++){
        int r = r0 + wave * 4 + j;
        hbf[(size_t)r * (D / 2) + lane] = f2bf2(acc[j].x, acc[j].y);
    }
}

// out[n] = m[n] * ( dinv[n]*(dinv[n]*h[n] + sum_e dinv[s]*h[s]) + bias )
// One wave per node; lane owns 2 output dims.
__global__ __launch_bounds__(256) void agg_kernel(const unsigned* __restrict__ hbf,
                                                  const float* __restrict__ dinv,
                                                  const int* __restrict__ rowofs,
                                                  const int* __restrict__ cursor,
                                                  const int* __restrict__ elist,
                                                  const int* __restrict__ mask,
                                                  const float* __restrict__ bias,
                                                  float* __restrict__ out){
    const int t = threadIdx.x;
    const int wave = t >> 6, lane = t & 63;
    const int n = blockIdx.x * 4 + wave;     // NN % 4 == 0
    float2* outp = (float2*)&out[(size_t)n * D + 2 * lane];
    if(!mask[n]){
        *outp = make_float2(0.f, 0.f);
        return;
    }
    const float dn = dinv[n];
    float2 hs = bf2f2(hbf[(size_t)n * (D / 2) + lane]);   // self-loop
    float2 acc = make_float2(dn * hs.x, dn * hs.y);
    const int base = rowofs[n];
    const int len  = cursor[n];
    for(int j = 0; j < len; j++){
        int s = elist[base + j];
        float ds = dinv[s];
        float2 hv = bf2f2(hbf[(size_t)s * (D / 2) + lane]);
        acc.x += ds * hv.x;
        acc.y += ds * hv.y;
    }
    float2 b = *(const float2*)&bias[2 * lane];
    outp->x = dn * acc.x + b.x;
    outp->y = dn * acc.y + b.y;
}

extern "C" void kernel_launch(void* const* d_in, const int* in_sizes, int n_in,
                              void* d_out, int out_size, void* d_ws, size_t ws_size,
                              hipStream_t stream){
    const float* x    = (const float*)d_in[0];
    const float* W    = (const float*)d_in[1];
    const float* bias = (const float*)d_in[2];
    const void*  eidx = d_in[3];
    const int*   mask = (const int*)d_in[4];
    float* out = (float*)d_out;

    char* ws = (char*)d_ws;
    int*      deg    = (int*)(ws + OFF_DEG);
    int*      rowofs = (int*)(ws + OFF_ROWOFS);
    int*      cursor = (int*)(ws + OFF_CURSOR);
    float*    dinv   = (float*)(ws + OFF_DINV);
    int*      flag   = (int*)(ws + OFF_FLAG);
    int*      part   = (int*)(ws + OFF_PART);
    int*      elist  = (int*)(ws + OFF_ELIST);
    unsigned* hbf    = (unsigned*)(ws + OFF_HBF);

    hipMemsetAsync(deg,    0, (size_t)NN * 4, stream);
    hipMemsetAsync(cursor, 0, (size_t)NN * 4, stream);
    detect_kernel <<<1,    64,  0, stream>>>(eidx, flag);
    count_kernel  <<<1024, 256, 0, stream>>>(eidx, flag, deg);
    scan1_kernel  <<<SCAN_BLOCKS, 1024, 0, stream>>>(deg, rowofs, part, dinv);
    scan2_kernel  <<<1,    128, 0, stream>>>(part);
    scan3_kernel  <<<SCAN_BLOCKS, 1024, 0, stream>>>(rowofs, part);
    scatter_kernel<<<1024, 256, 0, stream>>>(eidx, flag, mask, rowofs, cursor, elist);
    gemm_kernel   <<<NN/16,256, 0, stream>>>(x, W, mask, hbf);
    agg_kernel    <<<NN/4, 256, 0, stream>>>(hbf, dinv, rowofs, cursor, elist, mask, bias, out);
}

// Round 3
// 120.985 us; speedup vs baseline: 3.4711x; 1.7031x over previous
//
#include <hip/hip_runtime.h>
#include <hip/hip_bf16.h>

#define NN 100000
#define NE 625000
#define D  128
#define SCAN_BLOCKS 98   // 98*1024 >= NN

typedef __attribute__((ext_vector_type(8))) short bfrag;   // 8 bf16 (4 VGPRs)
typedef __attribute__((ext_vector_type(4))) float f32x4;   // MFMA accumulator

static constexpr size_t AL(size_t x){ return (x + 511) & ~(size_t)511; }
static constexpr size_t OFF_DEG    = 0;                             // int[NN]
static constexpr size_t OFF_ROWOFS = AL(OFF_DEG    + (size_t)NN*4); // int[NN]
static constexpr size_t OFF_CURSOR = AL(OFF_ROWOFS + (size_t)NN*4); // int[NN]
static constexpr size_t OFF_DINV   = AL(OFF_CURSOR + (size_t)NN*4); // float[NN]
static constexpr size_t OFF_FLAG   = AL(OFF_DINV   + (size_t)NN*4); // int[16]
static constexpr size_t OFF_PART   = AL(OFF_FLAG   + 64);           // int[128]
static constexpr size_t OFF_WT     = AL(OFF_PART   + 512);          // bf16[D*D] transposed W
static constexpr size_t OFF_ELIST  = AL(OFF_WT     + (size_t)D*D*2);// int[NE]
static constexpr size_t OFF_HBF    = AL(OFF_ELIST  + (size_t)NE*4); // bf16[NN*D]

// ---------- helpers ----------
__device__ inline unsigned short f2bf1(float a){
    // RNE f32 -> bf16 bits
    unsigned u = __float_as_uint(a);
    u += 0x7fffu + ((u >> 16) & 1u);
    return (unsigned short)(u >> 16);
}
__device__ inline float2 bf2f2(unsigned u){
    float2 r;
    r.x = __uint_as_float(u << 16);
    r.y = __uint_as_float(u & 0xffff0000u);
    return r;
}
__device__ inline int get_idx(const void* p, long long i, int is64){
    return is64 ? (int)((const long long*)p)[i] : ((const int*)p)[i];
}

// ---------- kernels ----------
// Detect whether edge_index buffer holds int64 (odd 32-bit words all zero) or int32.
__global__ void detect_kernel(const void* eidx, int* flag){
    if(blockIdx.x == 0 && threadIdx.x == 0){
        const int* p = (const int*)eidx;
        int allz = 1;
        for(int i = 1; i < 64; i += 2) allz &= (p[i] == 0);
        *flag = allz;  // 1 => int64 layout
    }
}

__global__ void count_kernel(const void* eidx, const int* __restrict__ flag,
                             int* __restrict__ deg){
    const int is64 = *flag;
    for(int e = blockIdx.x * blockDim.x + threadIdx.x; e < NE;
        e += gridDim.x * blockDim.x){
        int d = get_idx(eidx, (long long)NE + e, is64);
        atomicAdd(&deg[d], 1);
    }
}

// Hierarchical exclusive scan of deg -> rowofs (3 passes), fused dinv in pass 1.
__global__ __launch_bounds__(1024) void scan1_kernel(const int* __restrict__ deg,
                                                     int* __restrict__ rowofs,
                                                     int* __restrict__ partials,
                                                     float* __restrict__ dinv){
    __shared__ int s[1024];
    const int tid = threadIdx.x;
    const int i = blockIdx.x * 1024 + tid;
    const int v = (i < NN) ? deg[i] : 0;
    s[tid] = v;
    __syncthreads();
    for(int off = 1; off < 1024; off <<= 1){
        int u = (tid >= off) ? s[tid - off] : 0;
        __syncthreads();
        s[tid] += u;
        __syncthreads();
    }
    if(i < NN){
        rowofs[i] = s[tid] - v;                 // block-local exclusive
        dinv[i]   = rsqrtf((float)(v + 1));
    }
    if(tid == 1023) partials[blockIdx.x] = s[tid];
}

__global__ __launch_bounds__(128) void scan2_kernel(int* __restrict__ partials){
    __shared__ int s[128];
    const int tid = threadIdx.x;
    const int v = (tid < SCAN_BLOCKS) ? partials[tid] : 0;
    s[tid] = v;
    __syncthreads();
    for(int off = 1; off < 128; off <<= 1){
        int u = (tid >= off) ? s[tid - off] : 0;
        __syncthreads();
        s[tid] += u;
        __syncthreads();
    }
    if(tid < SCAN_BLOCKS) partials[tid] = s[tid] - v;   // exclusive block offsets
}

__global__ __launch_bounds__(1024) void scan3_kernel(int* __restrict__ rowofs,
                                                     const int* __restrict__ partials){
    const int i = blockIdx.x * 1024 + threadIdx.x;
    if(i < NN) rowofs[i] += partials[blockIdx.x];
}

// Scatter only unmasked->unmasked edges into CSR buckets; cursor = effective length.
__global__ void scatter_kernel(const void* eidx, const int* __restrict__ flag,
                               const int* __restrict__ mask,
                               const int* __restrict__ rowofs,
                               int* __restrict__ cursor, int* __restrict__ elist){
    const int is64 = *flag;
    for(int e = blockIdx.x * blockDim.x + threadIdx.x; e < NE;
        e += gridDim.x * blockDim.x){
        int s = get_idx(eidx, e, is64);
        int d = get_idx(eidx, (long long)NE + e, is64);
        if(mask[s] && mask[d]){
            int p = atomicAdd(&cursor[d], 1);
            elist[rowofs[d] + p] = s;
        }
    }
}

// W [k][n] f32 -> Wt [n][k] bf16  (coalesced read, scattered 2B write; tiny)
__global__ __launch_bounds__(256) void wconv_kernel(const float* __restrict__ W,
                                                    unsigned short* __restrict__ Wt){
    const int i = blockIdx.x * 256 + threadIdx.x;   // 16384 total
    const int k = i >> 7, n = i & 127;
    Wt[n * D + k] = f2bf1(W[i]);
}

// h = (x .* mask) @ W  via bf16 MFMA, stored bf16.
// Block: 256 thr / 4 waves, tile 64 rows x 128 cols, full K=128.
// LDS layout (both tiles): [row][k] bf16, 16B chunk kc swizzled by kc ^= (row&7).
__global__ __launch_bounds__(256) void gemm_kernel(const float* __restrict__ x,
                                                   const unsigned short* __restrict__ Wt,
                                                   const int* __restrict__ mask,
                                                   unsigned short* __restrict__ hb){
    __shared__ unsigned short xs[64 * D];    // 16 KB
    __shared__ unsigned short wl[D * D];     // 32 KB
    const int t = threadIdx.x;
    const int r0 = blockIdx.x * 64;

    // stage Wt -> LDS (swizzled): 2048 16B-chunks, 8 per thread, coalesced src
#pragma unroll
    for(int j = 0; j < 8; ++j){
        int c = t + 256 * j;
        int n = c >> 4, kc = c & 15;
        uint4 v = *(const uint4*)&Wt[n * D + kc * 8];
        *(uint4*)&wl[n * D + ((kc ^ (n & 7)) * 8)] = v;
    }
    // stage x (masked, f32->bf16) -> LDS (swizzled): 1024 chunks, 4 per thread
#pragma unroll
    for(int j = 0; j < 4; ++j){
        int c = t + 256 * j;
        int row = c >> 4, kc = c & 15;
        int r = r0 + row;
        float4 v0 = make_float4(0.f, 0.f, 0.f, 0.f), v1 = v0;
        float mv = 0.f;
        if(r < NN){
            mv = (float)mask[r];
            v0 = *(const float4*)&x[(size_t)r * D + kc * 8];
            v1 = *(const float4*)&x[(size_t)r * D + kc * 8 + 4];
        }
        uint4 pv;
        pv.x = (unsigned)f2bf1(v0.x * mv) | ((unsigned)f2bf1(v0.y * mv) << 16);
        pv.y = (unsigned)f2bf1(v0.z * mv) | ((unsigned)f2bf1(v0.w * mv) << 16);
        pv.z = (unsigned)f2bf1(v1.x * mv) | ((unsigned)f2bf1(v1.y * mv) << 16);
        pv.w = (unsigned)f2bf1(v1.z * mv) | ((unsigned)f2bf1(v1.w * mv) << 16);
        *(uint4*)&xs[row * D + ((kc ^ (row & 7)) * 8)] = pv;
    }
    __syncthreads();

    const int wv = t >> 6, lane = t & 63;
    const int r15 = lane & 15, quad = lane >> 4;
    const int sw = r15 & 7;          // (w*16+r15)&7 == r15&7 == (nf*16+r15)&7
    const int arow = wv * 16 + r15;

    f32x4 acc[8];
#pragma unroll
    for(int nf = 0; nf < 8; ++nf) acc[nf] = (f32x4){0.f, 0.f, 0.f, 0.f};

#pragma unroll
    for(int ks = 0; ks < 4; ++ks){
        int kc = (ks * 4 + quad) ^ sw;
        bfrag a = *(const bfrag*)&xs[arow * D + kc * 8];
#pragma unroll
        for(int nf = 0; nf < 8; ++nf){
            bfrag b = *(const bfrag*)&wl[(nf * 16 + r15) * D + kc * 8];
            acc[nf] = __builtin_amdgcn_mfma_f32_16x16x32_bf16(a, b, acc[nf], 0, 0, 0);
        }
    }
    // D layout: col = lane&15, row = (lane>>4)*4 + reg
#pragma unroll
    for(int nf = 0; nf < 8; ++nf){
#pragma unroll
        for(int j = 0; j < 4; ++j){
            int row = r0 + wv * 16 + quad * 4 + j;
            if(row < NN) hb[(size_t)row * D + nf * 16 + r15] = f2bf1(acc[nf][j]);
        }
    }
}

// out[n] = m[n] * ( dinv[n]*(dinv[n]*h[n] + sum_e dinv[s]*h[s]) + bias )
__global__ __launch_bounds__(256) void agg_kernel(const unsigned* __restrict__ hbf,
                                                  const float* __restrict__ dinv,
                                                  const int* __restrict__ rowofs,
                                                  const int* __restrict__ cursor,
                                                  const int* __restrict__ elist,
                                                  const int* __restrict__ mask,
                                                  const float* __restrict__ bias,
                                                  float* __restrict__ out){
    const int t = threadIdx.x;
    const int wave = t >> 6, lane = t & 63;
    const int n = blockIdx.x * 4 + wave;     // NN % 4 == 0
    float2* outp = (float2*)&out[(size_t)n * D + 2 * lane];
    if(!mask[n]){
        *outp = make_float2(0.f, 0.f);
        return;
    }
    const float dn = dinv[n];
    float2 hs = bf2f2(hbf[(size_t)n * (D / 2) + lane]);   // self-loop
    float2 acc = make_float2(dn * hs.x, dn * hs.y);
    const int base = rowofs[n];
    const int len  = cursor[n];
    for(int j = 0; j < len; j++){
        int s = elist[base + j];
        float ds = dinv[s];
        float2 hv = bf2f2(hbf[(size_t)s * (D / 2) + lane]);
        acc.x += ds * hv.x;
        acc.y += ds * hv.y;
    }
    float2 b = *(const float2*)&bias[2 * lane];
    outp->x = dn * acc.x + b.x;
    outp->y = dn * acc.y + b.y;
}

extern "C" void kernel_launch(void* const* d_in, const int* in_sizes, int n_in,
                              void* d_out, int out_size, void* d_ws, size_t ws_size,
                              hipStream_t stream){
    const float* x    = (const float*)d_in[0];
    const float* W    = (const float*)d_in[1];
    const float* bias = (const float*)d_in[2];
    const void*  eidx = d_in[3];
    const int*   mask = (const int*)d_in[4];
    float* out = (float*)d_out;

    char* ws = (char*)d_ws;
    int*            deg    = (int*)(ws + OFF_DEG);
    int*            rowofs = (int*)(ws + OFF_ROWOFS);
    int*            cursor = (int*)(ws + OFF_CURSOR);
    float*          dinv   = (float*)(ws + OFF_DINV);
    int*            flag   = (int*)(ws + OFF_FLAG);
    int*            part   = (int*)(ws + OFF_PART);
    unsigned short* wt     = (unsigned short*)(ws + OFF_WT);
    int*            elist  = (int*)(ws + OFF_ELIST);
    unsigned short* hb     = (unsigned short*)(ws + OFF_HBF);

    hipMemsetAsync(deg,    0, (size_t)NN * 4, stream);
    hipMemsetAsync(cursor, 0, (size_t)NN * 4, stream);
    detect_kernel <<<1,    64,  0, stream>>>(eidx, flag);
    count_kernel  <<<1024, 256, 0, stream>>>(eidx, flag, deg);
    scan1_kernel  <<<SCAN_BLOCKS, 1024, 0, stream>>>(deg, rowofs, part, dinv);
    scan2_kernel  <<<1,    128, 0, stream>>>(part);
    scan3_kernel  <<<SCAN_BLOCKS, 1024, 0, stream>>>(rowofs, part);
    scatter_kernel<<<1024, 256, 0, stream>>>(eidx, flag, mask, rowofs, cursor, elist);
    wconv_kernel  <<<D*D/256, 256, 0, stream>>>(W, wt);
    gemm_kernel   <<<(NN + 63)/64, 256, 0, stream>>>(x, wt, mask, hb);
    agg_kernel    <<<NN/4, 256, 0, stream>>>((const unsigned*)hb, dinv, rowofs, cursor,
                                             elist, mask, bias, out);
}

// Round 4
// 118.749 us; speedup vs baseline: 3.5365x; 1.0188x over previous
//
#include <hip/hip_runtime.h>
#include <hip/hip_bf16.h>

#define NN 100000
#define NE 625000
#define D  128
#define SCAN_BLOCKS 98   // 98*1024 >= NN

typedef __attribute__((ext_vector_type(8))) short bfrag;   // 8 bf16 (4 VGPRs)
typedef __attribute__((ext_vector_type(4))) float f32x4;   // MFMA accumulator

static constexpr size_t AL(size_t x){ return (x + 511) & ~(size_t)511; }
static constexpr size_t OFF_DEG    = 0;                             // int[NN]
static constexpr size_t OFF_ROWOFS = AL(OFF_DEG    + (size_t)NN*4); // int[NN]
static constexpr size_t OFF_CURSOR = AL(OFF_ROWOFS + (size_t)NN*4); // int[NN]
static constexpr size_t OFF_DINV   = AL(OFF_CURSOR + (size_t)NN*4); // float[NN]
static constexpr size_t OFF_FLAG   = AL(OFF_DINV   + (size_t)NN*4); // int[16]
static constexpr size_t OFF_PART   = AL(OFF_FLAG   + 64);           // int[128]
static constexpr size_t OFF_WT     = AL(OFF_PART   + 512);          // bf16[D*D] transposed W
static constexpr size_t OFF_ELIST  = AL(OFF_WT     + (size_t)D*D*2);// int[NE]
static constexpr size_t OFF_HBF    = AL(OFF_ELIST  + (size_t)NE*4); // bf16[NN*D]

// ---------- helpers ----------
__device__ inline unsigned short f2bf1(float a){
    // RNE f32 -> bf16 bits
    unsigned u = __float_as_uint(a);
    u += 0x7fffu + ((u >> 16) & 1u);
    return (unsigned short)(u >> 16);
}
__device__ inline float2 bf2f2(unsigned u){
    float2 r;
    r.x = __uint_as_float(u << 16);
    r.y = __uint_as_float(u & 0xffff0000u);
    return r;
}
__device__ inline int get_idx(const void* p, long long i, int is64){
    return is64 ? (int)((const long long*)p)[i] : ((const int*)p)[i];
}

// ---------- kernels ----------
// Zero deg + cursor (replaces two hipMemsetAsync whose runtime fill kernel ran at 9.8 GB/s).
__global__ __launch_bounds__(256) void zero_kernel(int4* __restrict__ deg4,
                                                   int4* __restrict__ cur4){
    const int i = blockIdx.x * 256 + threadIdx.x;   // NN/4 = 25000 int4 each
    if(i < NN / 4){
        deg4[i] = make_int4(0, 0, 0, 0);
        cur4[i] = make_int4(0, 0, 0, 0);
    }
}

// Detect whether edge_index buffer holds int64 (odd 32-bit words all zero) or int32.
__global__ void detect_kernel(const void* eidx, int* flag){
    if(blockIdx.x == 0 && threadIdx.x == 0){
        const int* p = (const int*)eidx;
        int allz = 1;
        for(int i = 1; i < 64; i += 2) allz &= (p[i] == 0);
        *flag = allz;  // 1 => int64 layout
    }
}

__global__ void count_kernel(const void* eidx, const int* __restrict__ flag,
                             int* __restrict__ deg){
    const int is64 = *flag;
    for(int e = blockIdx.x * blockDim.x + threadIdx.x; e < NE;
        e += gridDim.x * blockDim.x){
        int d = get_idx(eidx, (long long)NE + e, is64);
        atomicAdd(&deg[d], 1);
    }
}

// Hierarchical exclusive scan of deg -> rowofs (3 passes), fused dinv in pass 1.
__global__ __launch_bounds__(1024) void scan1_kernel(const int* __restrict__ deg,
                                                     int* __restrict__ rowofs,
                                                     int* __restrict__ partials,
                                                     float* __restrict__ dinv){
    __shared__ int s[1024];
    const int tid = threadIdx.x;
    const int i = blockIdx.x * 1024 + tid;
    const int v = (i < NN) ? deg[i] : 0;
    s[tid] = v;
    __syncthreads();
    for(int off = 1; off < 1024; off <<= 1){
        int u = (tid >= off) ? s[tid - off] : 0;
        __syncthreads();
        s[tid] += u;
        __syncthreads();
    }
    if(i < NN){
        rowofs[i] = s[tid] - v;                 // block-local exclusive
        dinv[i]   = rsqrtf((float)(v + 1));
    }
    if(tid == 1023) partials[blockIdx.x] = s[tid];
}

__global__ __launch_bounds__(128) void scan2_kernel(int* __restrict__ partials){
    __shared__ int s[128];
    const int tid = threadIdx.x;
    const int v = (tid < SCAN_BLOCKS) ? partials[tid] : 0;
    s[tid] = v;
    __syncthreads();
    for(int off = 1; off < 128; off <<= 1){
        int u = (tid >= off) ? s[tid - off] : 0;
        __syncthreads();
        s[tid] += u;
        __syncthreads();
    }
    if(tid < SCAN_BLOCKS) partials[tid] = s[tid] - v;   // exclusive block offsets
}

__global__ __launch_bounds__(1024) void scan3_kernel(int* __restrict__ rowofs,
                                                     const int* __restrict__ partials){
    const int i = blockIdx.x * 1024 + threadIdx.x;
    if(i < NN) rowofs[i] += partials[blockIdx.x];
}

// Scatter only unmasked->unmasked edges into CSR buckets; cursor = effective length.
__global__ void scatter_kernel(const void* eidx, const int* __restrict__ flag,
                               const int* __restrict__ mask,
                               const int* __restrict__ rowofs,
                               int* __restrict__ cursor, int* __restrict__ elist){
    const int is64 = *flag;
    for(int e = blockIdx.x * blockDim.x + threadIdx.x; e < NE;
        e += gridDim.x * blockDim.x){
        int s = get_idx(eidx, e, is64);
        int d = get_idx(eidx, (long long)NE + e, is64);
        if(mask[s] && mask[d]){
            int p = atomicAdd(&cursor[d], 1);
            elist[rowofs[d] + p] = s;
        }
    }
}

// W [k][n] f32 -> Wt [n][k] bf16  (coalesced read, scattered 2B write; tiny)
__global__ __launch_bounds__(256) void wconv_kernel(const float* __restrict__ W,
                                                    unsigned short* __restrict__ Wt){
    const int i = blockIdx.x * 256 + threadIdx.x;   // 16384 total
    const int k = i >> 7, n = i & 127;
    Wt[n * D + k] = f2bf1(W[i]);
}

// h = (x .* mask) @ W  via bf16 MFMA, stored bf16.
// Block: 256 thr / 4 waves, tile 64 rows x 128 cols, full K=128.
// LDS layout (both tiles): [row][k] bf16, 16B chunk kc swizzled by kc ^= (row&7).
__global__ __launch_bounds__(256) void gemm_kernel(const float* __restrict__ x,
                                                   const unsigned short* __restrict__ Wt,
                                                   const int* __restrict__ mask,
                                                   unsigned short* __restrict__ hb){
    __shared__ unsigned short xs[64 * D];    // 16 KB
    __shared__ unsigned short wl[D * D];     // 32 KB
    const int t = threadIdx.x;
    const int r0 = blockIdx.x * 64;

    // stage Wt -> LDS (swizzled): 2048 16B-chunks, 8 per thread, coalesced src
#pragma unroll
    for(int j = 0; j < 8; ++j){
        int c = t + 256 * j;
        int n = c >> 4, kc = c & 15;
        uint4 v = *(const uint4*)&Wt[n * D + kc * 8];
        *(uint4*)&wl[n * D + ((kc ^ (n & 7)) * 8)] = v;
    }
    // stage x (masked, f32->bf16) -> LDS (swizzled): 1024 chunks, 4 per thread
#pragma unroll
    for(int j = 0; j < 4; ++j){
        int c = t + 256 * j;
        int row = c >> 4, kc = c & 15;
        int r = r0 + row;
        float4 v0 = make_float4(0.f, 0.f, 0.f, 0.f), v1 = v0;
        float mv = 0.f;
        if(r < NN){
            mv = (float)mask[r];
            v0 = *(const float4*)&x[(size_t)r * D + kc * 8];
            v1 = *(const float4*)&x[(size_t)r * D + kc * 8 + 4];
        }
        uint4 pv;
        pv.x = (unsigned)f2bf1(v0.x * mv) | ((unsigned)f2bf1(v0.y * mv) << 16);
        pv.y = (unsigned)f2bf1(v0.z * mv) | ((unsigned)f2bf1(v0.w * mv) << 16);
        pv.z = (unsigned)f2bf1(v1.x * mv) | ((unsigned)f2bf1(v1.y * mv) << 16);
        pv.w = (unsigned)f2bf1(v1.z * mv) | ((unsigned)f2bf1(v1.w * mv) << 16);
        *(uint4*)&xs[row * D + ((kc ^ (row & 7)) * 8)] = pv;
    }
    __syncthreads();

    const int wv = t >> 6, lane = t & 63;
    const int r15 = lane & 15, quad = lane >> 4;
    const int sw = r15 & 7;          // (w*16+r15)&7 == r15&7 == (nf*16+r15)&7
    const int arow = wv * 16 + r15;

    f32x4 acc[8];
#pragma unroll
    for(int nf = 0; nf < 8; ++nf) acc[nf] = (f32x4){0.f, 0.f, 0.f, 0.f};

#pragma unroll
    for(int ks = 0; ks < 4; ++ks){
        int kc = (ks * 4 + quad) ^ sw;
        bfrag a = *(const bfrag*)&xs[arow * D + kc * 8];
#pragma unroll
        for(int nf = 0; nf < 8; ++nf){
            bfrag b = *(const bfrag*)&wl[(nf * 16 + r15) * D + kc * 8];
            acc[nf] = __builtin_amdgcn_mfma_f32_16x16x32_bf16(a, b, acc[nf], 0, 0, 0);
        }
    }
    // D layout: col = lane&15, row = (lane>>4)*4 + reg
#pragma unroll
    for(int nf = 0; nf < 8; ++nf){
#pragma unroll
        for(int j = 0; j < 4; ++j){
            int row = r0 + wv * 16 + quad * 4 + j;
            if(row < NN) hb[(size_t)row * D + nf * 16 + r15] = f2bf1(acc[nf][j]);
        }
    }
}

// out[n] = m[n] * ( dinv[n]*(dinv[n]*h[n] + sum_e dinv[s]*h[s]) + bias )
__global__ __launch_bounds__(256) void agg_kernel(const unsigned* __restrict__ hbf,
                                                  const float* __restrict__ dinv,
                                                  const int* __restrict__ rowofs,
                                                  const int* __restrict__ cursor,
                                                  const int* __restrict__ elist,
                                                  const int* __restrict__ mask,
                                                  const float* __restrict__ bias,
                                                  float* __restrict__ out){
    const int t = threadIdx.x;
    const int wave = t >> 6, lane = t & 63;
    const int n = blockIdx.x * 4 + wave;     // NN % 4 == 0
    float2* outp = (float2*)&out[(size_t)n * D + 2 * lane];
    if(!mask[n]){
        *outp = make_float2(0.f, 0.f);
        return;
    }
    const float dn = dinv[n];
    float2 hs = bf2f2(hbf[(size_t)n * (D / 2) + lane]);   // self-loop
    float2 acc = make_float2(dn * hs.x, dn * hs.y);
    const int base = rowofs[n];
    const int len  = cursor[n];
    for(int j = 0; j < len; j++){
        int s = elist[base + j];
        float ds = dinv[s];
        float2 hv = bf2f2(hbf[(size_t)s * (D / 2) + lane]);
        acc.x += ds * hv.x;
        acc.y += ds * hv.y;
    }
    float2 b = *(const float2*)&bias[2 * lane];
    outp->x = dn * acc.x + b.x;
    outp->y = dn * acc.y + b.y;
}

extern "C" void kernel_launch(void* const* d_in, const int* in_sizes, int n_in,
                              void* d_out, int out_size, void* d_ws, size_t ws_size,
                              hipStream_t stream){
    const float* x    = (const float*)d_in[0];
    const float* W    = (const float*)d_in[1];
    const float* bias = (const float*)d_in[2];
    const void*  eidx = d_in[3];
    const int*   mask = (const int*)d_in[4];
    float* out = (float*)d_out;

    char* ws = (char*)d_ws;
    int*            deg    = (int*)(ws + OFF_DEG);
    int*            rowofs = (int*)(ws + OFF_ROWOFS);
    int*            cursor = (int*)(ws + OFF_CURSOR);
    float*          dinv   = (float*)(ws + OFF_DINV);
    int*            flag   = (int*)(ws + OFF_FLAG);
    int*            part   = (int*)(ws + OFF_PART);
    unsigned short* wt     = (unsigned short*)(ws + OFF_WT);
    int*            elist  = (int*)(ws + OFF_ELIST);
    unsigned short* hb     = (unsigned short*)(ws + OFF_HBF);

    zero_kernel   <<<(NN/4 + 255)/256, 256, 0, stream>>>((int4*)deg, (int4*)cursor);
    detect_kernel <<<1,    64,  0, stream>>>(eidx, flag);
    count_kernel  <<<1024, 256, 0, stream>>>(eidx, flag, deg);
    scan1_kernel  <<<SCAN_BLOCKS, 1024, 0, stream>>>(deg, rowofs, part, dinv);
    scan2_kernel  <<<1,    128, 0, stream>>>(part);
    scan3_kernel  <<<SCAN_BLOCKS, 1024, 0, stream>>>(rowofs, part);
    scatter_kernel<<<1024, 256, 0, stream>>>(eidx, flag, mask, rowofs, cursor, elist);
    wconv_kernel  <<<D*D/256, 256, 0, stream>>>(W, wt);
    gemm_kernel   <<<(NN + 63)/64, 256, 0, stream>>>(x, wt, mask, hb);
    agg_kernel    <<<NN/4, 256, 0, stream>>>((const unsigned*)hb, dinv, rowofs, cursor,
                                             elist, mask, bias, out);
}

// Round 5
// 106.732 us; speedup vs baseline: 3.9347x; 1.1126x over previous
//
#include <hip/hip_runtime.h>
#include <hip/hip_bf16.h>

#define NN 100000
#define NE 625000
#define D  128
#define SCAN_BLOCKS 98   // 98*1024 >= NN

typedef __attribute__((ext_vector_type(8))) short bfrag;   // 8 bf16 (4 VGPRs)
typedef __attribute__((ext_vector_type(4))) float f32x4;   // MFMA accumulator

static constexpr size_t AL(size_t x){ return (x + 511) & ~(size_t)511; }
static constexpr size_t OFF_DEG    = 0;                             // int[NN]
static constexpr size_t OFF_ROWOFS = AL(OFF_DEG    + (size_t)NN*4); // int[NN]
static constexpr size_t OFF_CURSOR = AL(OFF_ROWOFS + (size_t)NN*4); // int[NN]
static constexpr size_t OFF_DINV   = AL(OFF_CURSOR + (size_t)NN*4); // float[NN]
static constexpr size_t OFF_FLAG   = AL(OFF_DINV   + (size_t)NN*4); // int[16]
static constexpr size_t OFF_PART   = AL(OFF_FLAG   + 64);           // int[128]
static constexpr size_t OFF_WT     = AL(OFF_PART   + 512);          // bf16[D*D] transposed W
static constexpr size_t OFF_ELIST2 = AL(OFF_WT     + (size_t)D*D*2);// int2[NE] {src, dinv(src)}
static constexpr size_t OFF_HBF    = AL(OFF_ELIST2 + (size_t)NE*8); // bf16[NN*D]

// ---------- helpers ----------
__device__ inline unsigned short f2bf1(float a){
    unsigned u = __float_as_uint(a);
    u += 0x7fffu + ((u >> 16) & 1u);
    return (unsigned short)(u >> 16);
}
__device__ inline float2 bf2f2(unsigned u){
    float2 r;
    r.x = __uint_as_float(u << 16);
    r.y = __uint_as_float(u & 0xffff0000u);
    return r;
}
__device__ inline int get_idx(const void* p, long long i, int is64){
    return is64 ? (int)((const long long*)p)[i] : ((const int*)p)[i];
}

// ---------- kernels ----------
// prep: zero deg+cursor (blocks 0..97), detect int64-vs-int32 (block0/thread0),
// convert W [k][n] f32 -> Wt [n][k] bf16 (blocks 98..161).
__global__ __launch_bounds__(256) void prep_kernel(const void* eidx, int* __restrict__ flag,
                                                   const float* __restrict__ W,
                                                   unsigned short* __restrict__ Wt,
                                                   int4* __restrict__ deg4,
                                                   int4* __restrict__ cur4){
    const int b = blockIdx.x, t = threadIdx.x;
    if(b < SCAN_BLOCKS){
        const int i = b * 256 + t;
        if(i < NN / 4){
            deg4[i] = make_int4(0, 0, 0, 0);
            cur4[i] = make_int4(0, 0, 0, 0);
        }
        if(b == 0 && t == 0){
            const int* p = (const int*)eidx;
            int allz = 1;
            for(int k = 1; k < 64; k += 2) allz &= (p[k] == 0);
            *flag = allz;  // 1 => int64 layout
        }
    } else {
        const int i = (b - SCAN_BLOCKS) * 256 + t;   // 0..16383
        const int k = i >> 7, n = i & 127;
        Wt[n * D + k] = f2bf1(W[i]);
    }
}

__global__ void count_kernel(const void* eidx, const int* __restrict__ flag,
                             int* __restrict__ deg){
    const int is64 = *flag;
    for(int e = blockIdx.x * blockDim.x + threadIdx.x; e < NE;
        e += gridDim.x * blockDim.x){
        int d = get_idx(eidx, (long long)NE + e, is64);
        atomicAdd(&deg[d], 1);
    }
}

// Block-local exclusive scan of deg -> rowofs, per-block totals -> partials, fused dinv.
__global__ __launch_bounds__(1024) void scan1_kernel(const int* __restrict__ deg,
                                                     int* __restrict__ rowofs,
                                                     int* __restrict__ partials,
                                                     float* __restrict__ dinv){
    __shared__ int s[1024];
    const int tid = threadIdx.x;
    const int i = blockIdx.x * 1024 + tid;
    const int v = (i < NN) ? deg[i] : 0;
    s[tid] = v;
    __syncthreads();
    for(int off = 1; off < 1024; off <<= 1){
        int u = (tid >= off) ? s[tid - off] : 0;
        __syncthreads();
        s[tid] += u;
        __syncthreads();
    }
    if(i < NN){
        rowofs[i] = s[tid] - v;                 // block-local exclusive
        dinv[i]   = rsqrtf((float)(v + 1));
    }
    if(tid == 1023) partials[blockIdx.x] = s[tid];
}

__global__ __launch_bounds__(128) void scan2_kernel(int* __restrict__ partials){
    __shared__ int s[128];
    const int tid = threadIdx.x;
    const int v = (tid < SCAN_BLOCKS) ? partials[tid] : 0;
    s[tid] = v;
    __syncthreads();
    for(int off = 1; off < 128; off <<= 1){
        int u = (tid >= off) ? s[tid - off] : 0;
        __syncthreads();
        s[tid] += u;
        __syncthreads();
    }
    if(tid < SCAN_BLOCKS) partials[tid] = s[tid] - v;   // exclusive block offsets
}

// Scatter unmasked->unmasked edges: elist2[slot] = {src, bits(dinv[src])}.
// Global row offset = rowofs[d] + partials[d>>10] (scan3 folded in here).
__global__ void scatter_kernel(const void* eidx, const int* __restrict__ flag,
                               const int* __restrict__ mask,
                               const int* __restrict__ rowofs,
                               const int* __restrict__ partials,
                               const float* __restrict__ dinv,
                               int* __restrict__ cursor, int2* __restrict__ elist2){
    const int is64 = *flag;
    for(int e = blockIdx.x * blockDim.x + threadIdx.x; e < NE;
        e += gridDim.x * blockDim.x){
        int s = get_idx(eidx, e, is64);
        int d = get_idx(eidx, (long long)NE + e, is64);
        if(mask[s] && mask[d]){
            int p = atomicAdd(&cursor[d], 1);
            elist2[rowofs[d] + partials[d >> 10] + p] =
                make_int2(s, __float_as_int(dinv[s]));
        }
    }
}

// h = (x .* mask) @ W via bf16 MFMA, stored bf16. Masked rows: no x load, no h store.
// Block: 256 thr / 4 waves, tile 64 rows x 128 cols, full K=128.
// LDS [row][k] bf16, 16B chunk kc swizzled by kc ^= (row&7).
__global__ __launch_bounds__(256) void gemm_kernel(const float* __restrict__ x,
                                                   const unsigned short* __restrict__ Wt,
                                                   const int* __restrict__ mask,
                                                   unsigned short* __restrict__ hb){
    __shared__ unsigned short xs[64 * D];    // 16 KB
    __shared__ unsigned short wl[D * D];     // 32 KB
    __shared__ int msk[64];
    const int t = threadIdx.x;
    const int r0 = blockIdx.x * 64;

    if(t < 64) msk[t] = (r0 + t < NN) ? mask[r0 + t] : 0;

    // stage Wt -> LDS (swizzled): 2048 16B-chunks, 8 per thread, coalesced src
#pragma unroll
    for(int j = 0; j < 8; ++j){
        int c = t + 256 * j;
        int n = c >> 4, kc = c & 15;
        uint4 v = *(const uint4*)&Wt[n * D + kc * 8];
        *(uint4*)&wl[n * D + ((kc ^ (n & 7)) * 8)] = v;
    }
    // stage x (masked, f32->bf16) -> LDS (swizzled): 1024 chunks, 4 per thread
#pragma unroll
    for(int j = 0; j < 4; ++j){
        int c = t + 256 * j;
        int row = c >> 4, kc = c & 15;
        int r = r0 + row;
        uint4 pv = make_uint4(0u, 0u, 0u, 0u);
        if(r < NN && mask[r]){
            float4 v0 = *(const float4*)&x[(size_t)r * D + kc * 8];
            float4 v1 = *(const float4*)&x[(size_t)r * D + kc * 8 + 4];
            pv.x = (unsigned)f2bf1(v0.x) | ((unsigned)f2bf1(v0.y) << 16);
            pv.y = (unsigned)f2bf1(v0.z) | ((unsigned)f2bf1(v0.w) << 16);
            pv.z = (unsigned)f2bf1(v1.x) | ((unsigned)f2bf1(v1.y) << 16);
            pv.w = (unsigned)f2bf1(v1.z) | ((unsigned)f2bf1(v1.w) << 16);
        }
        *(uint4*)&xs[row * D + ((kc ^ (row & 7)) * 8)] = pv;
    }
    __syncthreads();

    const int wv = t >> 6, lane = t & 63;
    const int r15 = lane & 15, quad = lane >> 4;
    const int sw = r15 & 7;
    const int arow = wv * 16 + r15;

    f32x4 acc[8];
#pragma unroll
    for(int nf = 0; nf < 8; ++nf) acc[nf] = (f32x4){0.f, 0.f, 0.f, 0.f};

#pragma unroll
    for(int ks = 0; ks < 4; ++ks){
        int kc = (ks * 4 + quad) ^ sw;
        bfrag a = *(const bfrag*)&xs[arow * D + kc * 8];
#pragma unroll
        for(int nf = 0; nf < 8; ++nf){
            bfrag b = *(const bfrag*)&wl[(nf * 16 + r15) * D + kc * 8];
            acc[nf] = __builtin_amdgcn_mfma_f32_16x16x32_bf16(a, b, acc[nf], 0, 0, 0);
        }
    }
    // D layout: col = lane&15, row = (lane>>4)*4 + reg
#pragma unroll
    for(int nf = 0; nf < 8; ++nf){
#pragma unroll
        for(int j = 0; j < 4; ++j){
            int lrow = wv * 16 + quad * 4 + j;
            int row = r0 + lrow;
            if(row < NN && msk[lrow])
                hb[(size_t)row * D + nf * 16 + r15] = f2bf1(acc[nf][j]);
        }
    }
}

// out[n] = m[n] * ( dinv[n]*(dinv[n]*h[n] + sum_e dinv[s]*h[s]) + bias )
// One wave per node; lane owns 2 dims. Edge list prefetched lane-parallel,
// broadcast via shfl, gathers 2-way unrolled.
__global__ __launch_bounds__(256) void agg_kernel(const unsigned* __restrict__ hbf,
                                                  const float* __restrict__ dinv,
                                                  const int* __restrict__ rowofs,
                                                  const int* __restrict__ cursor,
                                                  const int* __restrict__ partials,
                                                  const int2* __restrict__ elist2,
                                                  const int* __restrict__ mask,
                                                  const float* __restrict__ bias,
                                                  float* __restrict__ out){
    const int t = threadIdx.x;
    const int wave = t >> 6, lane = t & 63;
    const int n = blockIdx.x * 4 + wave;     // NN % 4 == 0
    float2* outp = (float2*)&out[(size_t)n * D + 2 * lane];
    if(!mask[n]){
        *outp = make_float2(0.f, 0.f);
        return;
    }
    const float dn = dinv[n];
    float2 hs = bf2f2(hbf[(size_t)n * (D / 2) + lane]);   // self-loop
    float2 acc  = make_float2(dn * hs.x, dn * hs.y);
    float2 acc2 = make_float2(0.f, 0.f);
    const int base = rowofs[n] + partials[n >> 10];
    const int len  = cursor[n];
    for(int j0 = 0; j0 < len; j0 += 64){
        const int m = min(64, len - j0);
        int2 u = make_int2(0, 0);
        if(lane < m) u = elist2[base + j0 + lane];
        int j = 0;
        for(; j + 1 < m; j += 2){
            int   s0 = __shfl(u.x, j),  s1 = __shfl(u.x, j + 1);
            float d0 = __int_as_float(__shfl(u.y, j));
            float d1 = __int_as_float(__shfl(u.y, j + 1));
            float2 h0 = bf2f2(hbf[(size_t)s0 * (D / 2) + lane]);
            float2 h1 = bf2f2(hbf[(size_t)s1 * (D / 2) + lane]);
            acc.x  += d0 * h0.x;  acc.y  += d0 * h0.y;
            acc2.x += d1 * h1.x;  acc2.y += d1 * h1.y;
        }
        if(j < m){
            int   s0 = __shfl(u.x, j);
            float d0 = __int_as_float(__shfl(u.y, j));
            float2 h0 = bf2f2(hbf[(size_t)s0 * (D / 2) + lane]);
            acc.x += d0 * h0.x;  acc.y += d0 * h0.y;
        }
    }
    float2 b = *(const float2*)&bias[2 * lane];
    outp->x = dn * (acc.x + acc2.x) + b.x;
    outp->y = dn * (acc.y + acc2.y) + b.y;
}

extern "C" void kernel_launch(void* const* d_in, const int* in_sizes, int n_in,
                              void* d_out, int out_size, void* d_ws, size_t ws_size,
                              hipStream_t stream){
    const float* x    = (const float*)d_in[0];
    const float* W    = (const float*)d_in[1];
    const float* bias = (const float*)d_in[2];
    const void*  eidx = d_in[3];
    const int*   mask = (const int*)d_in[4];
    float* out = (float*)d_out;

    char* ws = (char*)d_ws;
    int*            deg    = (int*)(ws + OFF_DEG);
    int*            rowofs = (int*)(ws + OFF_ROWOFS);
    int*            cursor = (int*)(ws + OFF_CURSOR);
    float*          dinv   = (float*)(ws + OFF_DINV);
    int*            flag   = (int*)(ws + OFF_FLAG);
    int*            part   = (int*)(ws + OFF_PART);
    unsigned short* wt     = (unsigned short*)(ws + OFF_WT);
    int2*           elist2 = (int2*)(ws + OFF_ELIST2);
    unsigned short* hb     = (unsigned short*)(ws + OFF_HBF);

    prep_kernel   <<<SCAN_BLOCKS + 64, 256, 0, stream>>>(eidx, flag, W, wt,
                                                         (int4*)deg, (int4*)cursor);
    count_kernel  <<<1024, 256, 0, stream>>>(eidx, flag, deg);
    scan1_kernel  <<<SCAN_BLOCKS, 1024, 0, stream>>>(deg, rowofs, part, dinv);
    scan2_kernel  <<<1,    128, 0, stream>>>(part);
    scatter_kernel<<<1024, 256, 0, stream>>>(eidx, flag, mask, rowofs, part, dinv,
                                             cursor, elist2);
    gemm_kernel   <<<(NN + 63)/64, 256, 0, stream>>>(x, wt, mask, hb);
    agg_kernel    <<<NN/4, 256, 0, stream>>>((const unsigned*)hb, dinv, rowofs, cursor,
                                             part, elist2, mask, bias, out);
}

// Round 6
// 98.978 us; speedup vs baseline: 4.2429x; 1.0783x over previous
//
#include <hip/hip_runtime.h>
#include <hip/hip_bf16.h>

#define NN 100000
#define NE 625000
#define D  128
#define SCAN_BLOCKS 98   // 98*1024 >= NN
#define SC_BLOCKS   512  // scatter blocks inside fused scatgemm launch

typedef __attribute__((ext_vector_type(8))) short bfrag;   // 8 bf16 (4 VGPRs)
typedef __attribute__((ext_vector_type(4))) float f32x4;   // MFMA accumulator

static constexpr size_t AL(size_t x){ return (x + 511) & ~(size_t)511; }
static constexpr size_t OFF_DEG    = 0;                             // int[NN]
static constexpr size_t OFF_ROWOFS = AL(OFF_DEG    + (size_t)NN*4); // int[NN]
static constexpr size_t OFF_CURSOR = AL(OFF_ROWOFS + (size_t)NN*4); // int[NN]
static constexpr size_t OFF_DINV   = AL(OFF_CURSOR + (size_t)NN*4); // float[NN] (0 if masked)
static constexpr size_t OFF_FLAG   = AL(OFF_DINV   + (size_t)NN*4); // int[16]: [0]=is64 [4]=done
static constexpr size_t OFF_PART   = AL(OFF_FLAG   + 64);           // int[128]
static constexpr size_t OFF_WT     = AL(OFF_PART   + 512);          // bf16[D*D] transposed W
static constexpr size_t OFF_ELIST2 = AL(OFF_WT     + (size_t)D*D*2);// int2[NE] {src, dinv(src)}
static constexpr size_t OFF_HBF    = AL(OFF_ELIST2 + (size_t)NE*8); // bf16[NN*D]

// ---------- helpers ----------
__device__ inline unsigned short f2bf1(float a){
    unsigned u = __float_as_uint(a);
    u += 0x7fffu + ((u >> 16) & 1u);
    return (unsigned short)(u >> 16);
}
__device__ inline float4 bf4f4(uint2 v){
    float4 r;
    r.x = __uint_as_float(v.x << 16);
    r.y = __uint_as_float(v.x & 0xffff0000u);
    r.z = __uint_as_float(v.y << 16);
    r.w = __uint_as_float(v.y & 0xffff0000u);
    return r;
}
__device__ inline int get_idx(const void* p, long long i, int is64){
    return is64 ? (int)((const long long*)p)[i] : ((const int*)p)[i];
}

// ---------- kernels ----------
// prep: zero deg+cursor+done, detect int64-vs-int32, W -> Wt bf16 transposed.
__global__ __launch_bounds__(256) void prep_kernel(const void* eidx, int* __restrict__ flag,
                                                   const float* __restrict__ W,
                                                   unsigned short* __restrict__ Wt,
                                                   int4* __restrict__ deg4,
                                                   int4* __restrict__ cur4){
    const int b = blockIdx.x, t = threadIdx.x;
    if(b < SCAN_BLOCKS){
        const int i = b * 256 + t;
        if(i < NN / 4){
            deg4[i] = make_int4(0, 0, 0, 0);
            cur4[i] = make_int4(0, 0, 0, 0);
        }
        if(b == 0 && t == 0){
            const int* p = (const int*)eidx;
            int allz = 1;
            for(int k = 1; k < 64; k += 2) allz &= (p[k] == 0);
            flag[0] = allz;  // 1 => int64 layout
            flag[4] = 0;     // scan 'done' ticket
        }
    } else {
        const int i = (b - SCAN_BLOCKS) * 256 + t;   // 0..16383
        const int k = i >> 7, n = i & 127;
        Wt[n * D + k] = f2bf1(W[i]);
    }
}

__global__ void count_kernel(const void* eidx, const int* __restrict__ flag,
                             int* __restrict__ deg){
    const int is64 = flag[0];
    for(int e = blockIdx.x * blockDim.x + threadIdx.x; e < NE;
        e += gridDim.x * blockDim.x){
        int d = get_idx(eidx, (long long)NE + e, is64);
        atomicAdd(&deg[d], 1);
    }
}

// Block-local exclusive scan of deg -> rowofs + masked dinv; the LAST finishing
// block (device-scope ticket) exclusive-scans the 98 per-block partials in place.
__global__ __launch_bounds__(1024) void scan12_kernel(const int* __restrict__ deg,
                                                      int* __restrict__ rowofs,
                                                      int* __restrict__ partials,
                                                      float* __restrict__ dinv,
                                                      const int* __restrict__ mask,
                                                      int* __restrict__ done){
    __shared__ int s[1024];
    __shared__ int amlast;
    const int tid = threadIdx.x;
    const int i = blockIdx.x * 1024 + tid;
    const int v = (i < NN) ? deg[i] : 0;
    s[tid] = v;
    __syncthreads();
    for(int off = 1; off < 1024; off <<= 1){
        int u = (tid >= off) ? s[tid - off] : 0;
        __syncthreads();
        s[tid] += u;
        __syncthreads();
    }
    if(i < NN){
        rowofs[i] = s[tid] - v;                        // block-local exclusive
        dinv[i]   = mask[i] ? rsqrtf((float)(v + 1)) : 0.f;
    }
    if(tid == 1023){
        partials[blockIdx.x] = s[tid];
        __threadfence();                               // release partials store
        int tk = atomicAdd(done, 1);
        amlast = (tk == SCAN_BLOCKS - 1);
    }
    __syncthreads();
    if(amlast){
        __threadfence();                               // acquire before reads
        int pv = (tid < SCAN_BLOCKS) ? atomicOr(&partials[tid], 0) : 0;
        s[tid] = pv;
        __syncthreads();
        for(int off = 1; off < 128; off <<= 1){
            int u = (tid >= off) ? s[tid - off] : 0;
            __syncthreads();
            s[tid] += u;
            __syncthreads();
        }
        if(tid < SCAN_BLOCKS) partials[tid] = s[tid] - pv;   // exclusive offsets
    }
}

// Fused launch: blocks [0,SC_BLOCKS) scatter edges into CSR; rest run the MFMA GEMM.
// (independent phases: scatter needs the scan, gemm needs only x/W/mask)
__global__ __launch_bounds__(256) void scatgemm_kernel(const void* eidx,
                                                       const int* __restrict__ flag,
                                                       const float* __restrict__ x,
                                                       const unsigned short* __restrict__ Wt,
                                                       const int* __restrict__ mask,
                                                       unsigned short* __restrict__ hb,
                                                       const int* __restrict__ rowofs,
                                                       const int* __restrict__ partials,
                                                       const float* __restrict__ dinv,
                                                       int* __restrict__ cursor,
                                                       int2* __restrict__ elist2){
    __shared__ unsigned short xs[64 * D];    // 16 KB
    __shared__ unsigned short wl[D * D];     // 32 KB
    __shared__ int msk[64];
    const int t = threadIdx.x;

    if(blockIdx.x < SC_BLOCKS){
        // ----- scatter: keep only unmasked->unmasked edges (dinv==0 encodes masked)
        const int is64 = flag[0];
        for(int e = blockIdx.x * 256 + t; e < NE; e += SC_BLOCKS * 256){
            int s = get_idx(eidx, e, is64);
            int d = get_idx(eidx, (long long)NE + e, is64);
            float ds = dinv[s];
            if(ds != 0.f && dinv[d] != 0.f){
                int p = atomicAdd(&cursor[d], 1);
                elist2[rowofs[d] + partials[d >> 10] + p] =
                    make_int2(s, __float_as_int(ds));
            }
        }
        return;
    }

    // ----- gemm: h = (x .* mask) @ W via bf16 MFMA. 64 rows/block, full K=128.
    const int r0 = (blockIdx.x - SC_BLOCKS) * 64;
    if(t < 64) msk[t] = (r0 + t < NN) ? mask[r0 + t] : 0;

#pragma unroll
    for(int j = 0; j < 8; ++j){              // stage Wt (swizzled): kc ^= row&7
        int c = t + 256 * j;
        int n = c >> 4, kc = c & 15;
        uint4 v = *(const uint4*)&Wt[n * D + kc * 8];
        *(uint4*)&wl[n * D + ((kc ^ (n & 7)) * 8)] = v;
    }
#pragma unroll
    for(int j = 0; j < 4; ++j){              // stage x (masked, f32->bf16, swizzled)
        int c = t + 256 * j;
        int row = c >> 4, kc = c & 15;
        int r = r0 + row;
        uint4 pv = make_uint4(0u, 0u, 0u, 0u);
        if(r < NN && mask[r]){
            float4 v0 = *(const float4*)&x[(size_t)r * D + kc * 8];
            float4 v1 = *(const float4*)&x[(size_t)r * D + kc * 8 + 4];
            pv.x = (unsigned)f2bf1(v0.x) | ((unsigned)f2bf1(v0.y) << 16);
            pv.y = (unsigned)f2bf1(v0.z) | ((unsigned)f2bf1(v0.w) << 16);
            pv.z = (unsigned)f2bf1(v1.x) | ((unsigned)f2bf1(v1.y) << 16);
            pv.w = (unsigned)f2bf1(v1.z) | ((unsigned)f2bf1(v1.w) << 16);
        }
        *(uint4*)&xs[row * D + ((kc ^ (row & 7)) * 8)] = pv;
    }
    __syncthreads();

    const int wv = t >> 6, lane = t & 63;
    const int r15 = lane & 15, quad = lane >> 4;
    const int sw = r15 & 7;
    const int arow = wv * 16 + r15;

    f32x4 acc[8];
#pragma unroll
    for(int nf = 0; nf < 8; ++nf) acc[nf] = (f32x4){0.f, 0.f, 0.f, 0.f};

#pragma unroll
    for(int ks = 0; ks < 4; ++ks){
        int kc = (ks * 4 + quad) ^ sw;
        bfrag a = *(const bfrag*)&xs[arow * D + kc * 8];
#pragma unroll
        for(int nf = 0; nf < 8; ++nf){
            bfrag b = *(const bfrag*)&wl[(nf * 16 + r15) * D + kc * 8];
            acc[nf] = __builtin_amdgcn_mfma_f32_16x16x32_bf16(a, b, acc[nf], 0, 0, 0);
        }
    }
    // D layout: col = lane&15, row = (lane>>4)*4 + reg
#pragma unroll
    for(int nf = 0; nf < 8; ++nf){
#pragma unroll
        for(int j = 0; j < 4; ++j){
            int lrow = wv * 16 + quad * 4 + j;
            int row = r0 + lrow;
            if(row < NN && msk[lrow])
                hb[(size_t)row * D + nf * 16 + r15] = f2bf1(acc[nf][j]);
        }
    }
}

// out[n] = m[n] * ( dinv[n]*(dinv[n]*h[n] + sum_e dinv[s]*h[s]) + bias )
// One wave = TWO nodes: lanes 0-31 -> node A, lanes 32-63 -> node B.
// Lane owns 4 dims (uint2 bf16 gathers, float4 out writes).
__global__ __launch_bounds__(256) void agg_kernel(const uint2* __restrict__ hb2,
                                                  const float* __restrict__ dinv,
                                                  const int* __restrict__ rowofs,
                                                  const int* __restrict__ cursor,
                                                  const int* __restrict__ partials,
                                                  const int2* __restrict__ elist2,
                                                  const float* __restrict__ bias,
                                                  float* __restrict__ out){
    const int t = threadIdx.x;
    const int wave = t >> 6, lane = t & 63;
    const int half = lane >> 5, hl = lane & 31;
    const int n = blockIdx.x * 8 + wave * 2 + half;   // NN % 8 == 0
    const float dn = dinv[n];                          // 0 => masked node
    const int len  = cursor[n];                        // 0 for masked nodes
    const int base = rowofs[n] + partials[n >> 10];

    float4 h = bf4f4(hb2[(size_t)n * 32 + hl]);        // self-loop (garbage*0 if masked)
    float4 a0, a1;
    a0.x = dn * h.x; a0.y = dn * h.y; a0.z = dn * h.z; a0.w = dn * h.w;
    a1 = make_float4(0.f, 0.f, 0.f, 0.f);

    const int lenmax = max(len, __shfl(len, lane ^ 32));
    for(int j0 = 0; j0 < lenmax; j0 += 32){
        int2 u = make_int2(0, 0);
        if(j0 + hl < len) u = elist2[base + j0 + hl];
        const int mm = min(32, lenmax - j0);
        int j = 0;
        for(; j + 1 < mm; j += 2){
            int   s0 = __shfl(u.x, half * 32 + j);
            int   s1 = __shfl(u.x, half * 32 + j + 1);
            float d0 = __int_as_float(__shfl(u.y, half * 32 + j));
            float d1 = __int_as_float(__shfl(u.y, half * 32 + j + 1));
            if(j0 + j < len){
                float4 hv = bf4f4(hb2[(size_t)s0 * 32 + hl]);
                a0.x += d0 * hv.x; a0.y += d0 * hv.y;
                a0.z += d0 * hv.z; a0.w += d0 * hv.w;
            }
            if(j0 + j + 1 < len){
                float4 hv = bf4f4(hb2[(size_t)s1 * 32 + hl]);
                a1.x += d1 * hv.x; a1.y += d1 * hv.y;
                a1.z += d1 * hv.z; a1.w += d1 * hv.w;
            }
        }
        if(j < mm && j0 + j < len){
            int   s0 = __shfl(u.x, half * 32 + j);
            float d0 = __int_as_float(__shfl(u.y, half * 32 + j));
            float4 hv = bf4f4(hb2[(size_t)s0 * 32 + hl]);
            a0.x += d0 * hv.x; a0.y += d0 * hv.y;
            a0.z += d0 * hv.z; a0.w += d0 * hv.w;
        }
    }
    float4 b = ((const float4*)bias)[hl];
    float4 o;
    if(dn != 0.f){
        o.x = dn * (a0.x + a1.x) + b.x;
        o.y = dn * (a0.y + a1.y) + b.y;
        o.z = dn * (a0.z + a1.z) + b.z;
        o.w = dn * (a0.w + a1.w) + b.w;
    } else {
        o = make_float4(0.f, 0.f, 0.f, 0.f);
    }
    ((float4*)out)[(size_t)n * 32 + hl] = o;
}

extern "C" void kernel_launch(void* const* d_in, const int* in_sizes, int n_in,
                              void* d_out, int out_size, void* d_ws, size_t ws_size,
                              hipStream_t stream){
    const float* x    = (const float*)d_in[0];
    const float* W    = (const float*)d_in[1];
    const float* bias = (const float*)d_in[2];
    const void*  eidx = d_in[3];
    const int*   mask = (const int*)d_in[4];
    float* out = (float*)d_out;

    char* ws = (char*)d_ws;
    int*            deg    = (int*)(ws + OFF_DEG);
    int*            rowofs = (int*)(ws + OFF_ROWOFS);
    int*            cursor = (int*)(ws + OFF_CURSOR);
    float*          dinv   = (float*)(ws + OFF_DINV);
    int*            flag   = (int*)(ws + OFF_FLAG);
    int*            part   = (int*)(ws + OFF_PART);
    unsigned short* wt     = (unsigned short*)(ws + OFF_WT);
    int2*           elist2 = (int2*)(ws + OFF_ELIST2);
    unsigned short* hb     = (unsigned short*)(ws + OFF_HBF);

    const int GEMM_BLOCKS = (NN + 63) / 64;
    prep_kernel    <<<SCAN_BLOCKS + 64, 256, 0, stream>>>(eidx, flag, W, wt,
                                                          (int4*)deg, (int4*)cursor);
    count_kernel   <<<1024, 256, 0, stream>>>(eidx, flag, deg);
    scan12_kernel  <<<SCAN_BLOCKS, 1024, 0, stream>>>(deg, rowofs, part, dinv,
                                                      mask, flag + 4);
    scatgemm_kernel<<<SC_BLOCKS + GEMM_BLOCKS, 256, 0, stream>>>(eidx, flag, x, wt, mask,
                                                                 hb, rowofs, part, dinv,
                                                                 cursor, elist2);
    agg_kernel     <<<NN/8, 256, 0, stream>>>((const uint2*)hb, dinv, rowofs, cursor,
                                              part, elist2, bias, out);
}

// Round 7
// 96.424 us; speedup vs baseline: 4.3553x; 1.0265x over previous
//
#include <hip/hip_runtime.h>
#include <hip/hip_bf16.h>

#define NN 100000
#define NE 625000
#define D  128
#define SCAN_BLOCKS 98    // 98*1024 >= NN
#define CNT_BLOCKS  256   // count blocks fused ahead of gemm
#define GEMM_ROWS   128
#define GEMM_BLOCKS ((NN + GEMM_ROWS - 1) / GEMM_ROWS)   // 782

typedef __attribute__((ext_vector_type(8))) short bfrag;   // 8 bf16 (4 VGPRs)
typedef __attribute__((ext_vector_type(4))) float f32x4;   // MFMA accumulator

static constexpr size_t AL(size_t x){ return (x + 511) & ~(size_t)511; }
static constexpr size_t OFF_DEG    = 0;                             // int[NN]
static constexpr size_t OFF_ROWOFS = AL(OFF_DEG    + (size_t)NN*4); // int[NN]
static constexpr size_t OFF_CURSOR = AL(OFF_ROWOFS + (size_t)NN*4); // int[NN]
static constexpr size_t OFF_DINV   = AL(OFF_CURSOR + (size_t)NN*4); // float[NN] (0 if masked)
static constexpr size_t OFF_FLAG   = AL(OFF_DINV   + (size_t)NN*4); // int[16]: [0]=is64 [4]=done
static constexpr size_t OFF_PART   = AL(OFF_FLAG   + 64);           // int[128]
static constexpr size_t OFF_WT     = AL(OFF_PART   + 512);          // bf16[D*D] transposed W
static constexpr size_t OFF_ELIST2 = AL(OFF_WT     + (size_t)D*D*2);// int2[NE] {src, dinv(src)}
static constexpr size_t OFF_HBF    = AL(OFF_ELIST2 + (size_t)NE*8); // bf16[NN*D]

// ---------- helpers ----------
__device__ inline unsigned short f2bf1(float a){
    unsigned u = __float_as_uint(a);
    u += 0x7fffu + ((u >> 16) & 1u);
    return (unsigned short)(u >> 16);
}
__device__ inline float4 bf4f4(uint2 v){
    float4 r;
    r.x = __uint_as_float(v.x << 16);
    r.y = __uint_as_float(v.x & 0xffff0000u);
    r.z = __uint_as_float(v.y << 16);
    r.w = __uint_as_float(v.y & 0xffff0000u);
    return r;
}
__device__ inline int get_idx(const void* p, long long i, int is64){
    return is64 ? (int)((const long long*)p)[i] : ((const int*)p)[i];
}

// ---------- kernels ----------
// prep: zero deg+cursor+done, detect int64-vs-int32, W -> Wt bf16 transposed.
__global__ __launch_bounds__(256) void prep_kernel(const void* eidx, int* __restrict__ flag,
                                                   const float* __restrict__ W,
                                                   unsigned short* __restrict__ Wt,
                                                   int4* __restrict__ deg4,
                                                   int4* __restrict__ cur4){
    const int b = blockIdx.x, t = threadIdx.x;
    if(b < SCAN_BLOCKS){
        const int i = b * 256 + t;
        if(i < NN / 4){
            deg4[i] = make_int4(0, 0, 0, 0);
            cur4[i] = make_int4(0, 0, 0, 0);
        }
        if(b == 0 && t == 0){
            const int* p = (const int*)eidx;
            int allz = 1;
            for(int k = 1; k < 64; k += 2) allz &= (p[k] == 0);
            flag[0] = allz;  // 1 => int64 layout
            flag[4] = 0;     // scan 'done' ticket
        }
    } else {
        const int i = (b - SCAN_BLOCKS) * 256 + t;   // 0..16383
        const int k = i >> 7, n = i & 127;
        Wt[n * D + k] = f2bf1(W[i]);
    }
}

// Fused launch: blocks [0,CNT_BLOCKS) count in-degrees; the rest run the MFMA GEMM
// (independent: count touches deg only, gemm touches x/Wt/mask/hb).
// GEMM: h = (x .* mask) @ W, bf16 out. 128 rows/block, 4 waves (32 rows each, 2 groups).
// A-frags loaded per-lane directly from global x (2x float4 -> cvt), W in swizzled LDS.
__global__ __launch_bounds__(256, 4) void gemmcount_kernel(
        const void* eidx, const int* __restrict__ flag, int* __restrict__ deg,
        const float* __restrict__ x, const unsigned short* __restrict__ Wt,
        const int* __restrict__ mask, unsigned short* __restrict__ hb){
    __shared__ unsigned short wl[D * D];     // 32 KB
    __shared__ int msk[GEMM_ROWS];
    const int t = threadIdx.x;

    if(blockIdx.x < CNT_BLOCKS){
        const int is64 = flag[0];
        for(int e = blockIdx.x * 256 + t; e < NE; e += CNT_BLOCKS * 256){
            int d = get_idx(eidx, (long long)NE + e, is64);
            atomicAdd(&deg[d], 1);
        }
        return;
    }

    const int r0 = (blockIdx.x - CNT_BLOCKS) * GEMM_ROWS;
#pragma unroll
    for(int j = 0; j < 8; ++j){              // stage Wt (swizzled): chunk kc -> kc^(n&7)
        int c = t + 256 * j;
        int n = c >> 4, kc = c & 15;
        uint4 v = *(const uint4*)&Wt[n * D + kc * 8];
        *(uint4*)&wl[n * D + ((kc ^ (n & 7)) * 8)] = v;
    }
    if(t < GEMM_ROWS) msk[t] = (r0 + t < NN) ? mask[r0 + t] : 0;
    __syncthreads();

    const int wv = t >> 6, lane = t & 63;
    const int r15 = lane & 15, quad = lane >> 4;
    const int sw = r15 & 7;

    f32x4 acc[2][8];
#pragma unroll
    for(int g = 0; g < 2; ++g)
#pragma unroll
        for(int nf = 0; nf < 8; ++nf) acc[g][nf] = (f32x4){0.f, 0.f, 0.f, 0.f};

#pragma unroll 2
    for(int ks = 0; ks < 4; ++ks){
        const int kq = ks * 4 + quad;        // actual k-chunk (8 elems)
        bfrag a[2];
#pragma unroll
        for(int g = 0; g < 2; ++g){
            const int lrow = wv * 32 + g * 16 + r15;
            const int arow = r0 + lrow;
            bfrag av = (bfrag){0,0,0,0,0,0,0,0};
            if(arow < NN && msk[lrow]){
                float4 u = *(const float4*)&x[(size_t)arow * D + kq * 8];
                float4 v = *(const float4*)&x[(size_t)arow * D + kq * 8 + 4];
                av[0] = (short)f2bf1(u.x); av[1] = (short)f2bf1(u.y);
                av[2] = (short)f2bf1(u.z); av[3] = (short)f2bf1(u.w);
                av[4] = (short)f2bf1(v.x); av[5] = (short)f2bf1(v.y);
                av[6] = (short)f2bf1(v.z); av[7] = (short)f2bf1(v.w);
            }
            a[g] = av;
        }
        const int kc = kq ^ sw;              // swizzled position holding chunk kq
#pragma unroll
        for(int nf = 0; nf < 8; ++nf){
            bfrag b = *(const bfrag*)&wl[(nf * 16 + r15) * D + kc * 8];
            acc[0][nf] = __builtin_amdgcn_mfma_f32_16x16x32_bf16(a[0], b, acc[0][nf], 0, 0, 0);
            acc[1][nf] = __builtin_amdgcn_mfma_f32_16x16x32_bf16(a[1], b, acc[1][nf], 0, 0, 0);
        }
    }
    // D layout: col = lane&15, row = (lane>>4)*4 + reg
#pragma unroll
    for(int g = 0; g < 2; ++g)
#pragma unroll
        for(int nf = 0; nf < 8; ++nf)
#pragma unroll
            for(int j = 0; j < 4; ++j){
                int lrow = wv * 32 + g * 16 + quad * 4 + j;
                int row = r0 + lrow;
                if(row < NN && msk[lrow])
                    hb[(size_t)row * D + nf * 16 + r15] = f2bf1(acc[g][nf][j]);
            }
}

// Block-local exclusive scan of deg -> rowofs + masked dinv; the LAST finishing
// block (device-scope ticket) exclusive-scans the 98 per-block partials in place.
__global__ __launch_bounds__(1024) void scan12_kernel(const int* __restrict__ deg,
                                                      int* __restrict__ rowofs,
                                                      int* __restrict__ partials,
                                                      float* __restrict__ dinv,
                                                      const int* __restrict__ mask,
                                                      int* __restrict__ done){
    __shared__ int s[1024];
    __shared__ int amlast;
    const int tid = threadIdx.x;
    const int i = blockIdx.x * 1024 + tid;
    const int v = (i < NN) ? deg[i] : 0;
    s[tid] = v;
    __syncthreads();
    for(int off = 1; off < 1024; off <<= 1){
        int u = (tid >= off) ? s[tid - off] : 0;
        __syncthreads();
        s[tid] += u;
        __syncthreads();
    }
    if(i < NN){
        rowofs[i] = s[tid] - v;                        // block-local exclusive
        dinv[i]   = mask[i] ? rsqrtf((float)(v + 1)) : 0.f;
    }
    if(tid == 1023){
        partials[blockIdx.x] = s[tid];
        __threadfence();                               // release partials store
        int tk = atomicAdd(done, 1);
        amlast = (tk == SCAN_BLOCKS - 1);
    }
    __syncthreads();
    if(amlast){
        __threadfence();                               // acquire before reads
        int pv = (tid < SCAN_BLOCKS) ? atomicOr(&partials[tid], 0) : 0;
        s[tid] = pv;
        __syncthreads();
        for(int off = 1; off < 128; off <<= 1){
            int u = (tid >= off) ? s[tid - off] : 0;
            __syncthreads();
            s[tid] += u;
            __syncthreads();
        }
        if(tid < SCAN_BLOCKS) partials[tid] = s[tid] - pv;   // exclusive offsets
    }
}

// Scatter unmasked->unmasked edges (dinv==0 encodes masked): elist2 = {src, dinv[src]}.
__global__ __launch_bounds__(256) void scatter_kernel(const void* eidx,
                                                      const int* __restrict__ flag,
                                                      const int* __restrict__ rowofs,
                                                      const int* __restrict__ partials,
                                                      const float* __restrict__ dinv,
                                                      int* __restrict__ cursor,
                                                      int2* __restrict__ elist2){
    const int is64 = flag[0];
    for(int e = blockIdx.x * 256 + threadIdx.x; e < NE; e += gridDim.x * 256){
        int s = get_idx(eidx, e, is64);
        int d = get_idx(eidx, (long long)NE + e, is64);
        float ds = dinv[s];
        if(ds != 0.f && dinv[d] != 0.f){
            int p = atomicAdd(&cursor[d], 1);
            elist2[rowofs[d] + partials[d >> 10] + p] = make_int2(s, __float_as_int(ds));
        }
    }
}

// out[n] = m[n] * ( dinv[n]*(dinv[n]*h[n] + sum_e dinv[s]*h[s]) + bias )
// One wave = TWO nodes: lanes 0-31 node A, 32-63 node B; lane owns 4 dims.
__global__ __launch_bounds__(256) void agg_kernel(const uint2* __restrict__ hb2,
                                                  const float* __restrict__ dinv,
                                                  const int* __restrict__ rowofs,
                                                  const int* __restrict__ cursor,
                                                  const int* __restrict__ partials,
                                                  const int2* __restrict__ elist2,
                                                  const float* __restrict__ bias,
                                                  float* __restrict__ out){
    const int t = threadIdx.x;
    const int wave = t >> 6, lane = t & 63;
    const int half = lane >> 5, hl = lane & 31;
    const int n = blockIdx.x * 8 + wave * 2 + half;   // NN % 8 == 0
    const float dn = dinv[n];                          // 0 => masked node
    const int len  = cursor[n];                        // 0 for masked nodes
    const int base = rowofs[n] + partials[n >> 10];

    float4 h = bf4f4(hb2[(size_t)n * 32 + hl]);        // self-loop (x0 if masked)
    float4 a0, a1;
    a0.x = dn * h.x; a0.y = dn * h.y; a0.z = dn * h.z; a0.w = dn * h.w;
    a1 = make_float4(0.f, 0.f, 0.f, 0.f);

    const int lenmax = max(len, __shfl(len, lane ^ 32));
    for(int j0 = 0; j0 < lenmax; j0 += 32){
        int2 u = make_int2(0, 0);
        if(j0 + hl < len) u = elist2[base + j0 + hl];
        const int mm = min(32, lenmax - j0);
        int j = 0;
        for(; j + 1 < mm; j += 2){
            int   s0 = __shfl(u.x, half * 32 + j);
            int   s1 = __shfl(u.x, half * 32 + j + 1);
            float d0 = __int_as_float(__shfl(u.y, half * 32 + j));
            float d1 = __int_as_float(__shfl(u.y, half * 32 + j + 1));
            if(j0 + j < len){
                float4 hv = bf4f4(hb2[(size_t)s0 * 32 + hl]);
                a0.x += d0 * hv.x; a0.y += d0 * hv.y;
                a0.z += d0 * hv.z; a0.w += d0 * hv.w;
            }
            if(j0 + j + 1 < len){
                float4 hv = bf4f4(hb2[(size_t)s1 * 32 + hl]);
                a1.x += d1 * hv.x; a1.y += d1 * hv.y;
                a1.z += d1 * hv.z; a1.w += d1 * hv.w;
            }
        }
        if(j < mm && j0 + j < len){
            int   s0 = __shfl(u.x, half * 32 + j);
            float d0 = __int_as_float(__shfl(u.y, half * 32 + j));
            float4 hv = bf4f4(hb2[(size_t)s0 * 32 + hl]);
            a0.x += d0 * hv.x; a0.y += d0 * hv.y;
            a0.z += d0 * hv.z; a0.w += d0 * hv.w;
        }
    }
    float4 b = ((const float4*)bias)[hl];
    float4 o;
    if(dn != 0.f){
        o.x = dn * (a0.x + a1.x) + b.x;
        o.y = dn * (a0.y + a1.y) + b.y;
        o.z = dn * (a0.z + a1.z) + b.z;
        o.w = dn * (a0.w + a1.w) + b.w;
    } else {
        o = make_float4(0.f, 0.f, 0.f, 0.f);
    }
    ((float4*)out)[(size_t)n * 32 + hl] = o;
}

extern "C" void kernel_launch(void* const* d_in, const int* in_sizes, int n_in,
                              void* d_out, int out_size, void* d_ws, size_t ws_size,
                              hipStream_t stream){
    const float* x    = (const float*)d_in[0];
    const float* W    = (const float*)d_in[1];
    const float* bias = (const float*)d_in[2];
    const void*  eidx = d_in[3];
    const int*   mask = (const int*)d_in[4];
    float* out = (float*)d_out;

    char* ws = (char*)d_ws;
    int*            deg    = (int*)(ws + OFF_DEG);
    int*            rowofs = (int*)(ws + OFF_ROWOFS);
    int*            cursor = (int*)(ws + OFF_CURSOR);
    float*          dinv   = (float*)(ws + OFF_DINV);
    int*            flag   = (int*)(ws + OFF_FLAG);
    int*            part   = (int*)(ws + OFF_PART);
    unsigned short* wt     = (unsigned short*)(ws + OFF_WT);
    int2*           elist2 = (int2*)(ws + OFF_ELIST2);
    unsigned short* hb     = (unsigned short*)(ws + OFF_HBF);

    prep_kernel     <<<SCAN_BLOCKS + 64, 256, 0, stream>>>(eidx, flag, W, wt,
                                                           (int4*)deg, (int4*)cursor);
    gemmcount_kernel<<<CNT_BLOCKS + GEMM_BLOCKS, 256, 0, stream>>>(eidx, flag, deg,
                                                                   x, wt, mask, hb);
    scan12_kernel   <<<SCAN_BLOCKS, 1024, 0, stream>>>(deg, rowofs, part, dinv,
                                                       mask, flag + 4);
    scatter_kernel  <<<1024, 256, 0, stream>>>(eidx, flag, rowofs, part, dinv,
                                               cursor, elist2);
    agg_kernel      <<<NN/8, 256, 0, stream>>>((const uint2*)hb, dinv, rowofs, cursor,
                                               part, elist2, bias, out);
}

// Round 8
// 94.162 us; speedup vs baseline: 4.4599x; 1.0240x over previous
//
#include <hip/hip_runtime.h>
#include <hip/hip_bf16.h>

#define NN 100000
#define NE 625000
#define D  128
#define SCAN_BLOCKS 98    // 98*1024 >= NN
#define CNT_BLOCKS  256   // count blocks fused ahead of gemm
#define GEMM_ROWS   128
#define GEMM_BLOCKS ((NN + GEMM_ROWS - 1) / GEMM_ROWS)   // 782
#define TRP 136           // transpose LDS row pitch (shorts): 272B rows, 16B-aligned

typedef __attribute__((ext_vector_type(8))) short bfrag;   // 8 bf16 (4 VGPRs)
typedef __attribute__((ext_vector_type(4))) float f32x4;   // MFMA accumulator

static constexpr size_t AL(size_t x){ return (x + 511) & ~(size_t)511; }
static constexpr size_t OFF_DEG    = 0;                             // int[NN]
static constexpr size_t OFF_ROWOFS = AL(OFF_DEG    + (size_t)NN*4); // int[NN]
static constexpr size_t OFF_CURSOR = AL(OFF_ROWOFS + (size_t)NN*4); // int[NN]
static constexpr size_t OFF_DINV   = AL(OFF_CURSOR + (size_t)NN*4); // float[NN] (0 if masked)
static constexpr size_t OFF_FLAG   = AL(OFF_DINV   + (size_t)NN*4); // int[16]: [0]=is64 [4]=done
static constexpr size_t OFF_PART   = AL(OFF_FLAG   + 64);           // int[128]
static constexpr size_t OFF_WT     = AL(OFF_PART   + 512);          // bf16[D*D] transposed W
static constexpr size_t OFF_ELIST2 = AL(OFF_WT     + (size_t)D*D*2);// int2[NE] {src, dinv(src)}
static constexpr size_t OFF_HBF    = AL(OFF_ELIST2 + (size_t)NE*8); // bf16[NN*D]

// ---------- helpers ----------
__device__ inline unsigned short f2bf1(float a){
    unsigned u = __float_as_uint(a);
    u += 0x7fffu + ((u >> 16) & 1u);
    return (unsigned short)(u >> 16);
}
__device__ inline float4 bf4f4(uint2 v){
    float4 r;
    r.x = __uint_as_float(v.x << 16);
    r.y = __uint_as_float(v.x & 0xffff0000u);
    r.z = __uint_as_float(v.y << 16);
    r.w = __uint_as_float(v.y & 0xffff0000u);
    return r;
}
__device__ inline int get_idx(const void* p, long long i, int is64){
    return is64 ? (int)((const long long*)p)[i] : ((const int*)p)[i];
}

// ---------- kernels ----------
// prep: zero deg+cursor+done, detect int64-vs-int32, W -> Wt bf16 transposed.
__global__ __launch_bounds__(256) void prep_kernel(const void* eidx, int* __restrict__ flag,
                                                   const float* __restrict__ W,
                                                   unsigned short* __restrict__ Wt,
                                                   int4* __restrict__ deg4,
                                                   int4* __restrict__ cur4){
    const int b = blockIdx.x, t = threadIdx.x;
    if(b < SCAN_BLOCKS){
        const int i = b * 256 + t;
        if(i < NN / 4){
            deg4[i] = make_int4(0, 0, 0, 0);
            cur4[i] = make_int4(0, 0, 0, 0);
        }
        if(b == 0 && t == 0){
            const int* p = (const int*)eidx;
            int allz = 1;
            for(int k = 1; k < 64; k += 2) allz &= (p[k] == 0);
            flag[0] = allz;  // 1 => int64 layout
            flag[4] = 0;     // scan 'done' ticket
        }
    } else {
        const int i = (b - SCAN_BLOCKS) * 256 + t;   // 0..16383
        const int k = i >> 7, n = i & 127;
        Wt[n * D + k] = f2bf1(W[i]);
    }
}

// Fused launch: blocks [0,CNT_BLOCKS) count in-degrees; the rest run the MFMA GEMM.
// GEMM: h = (x .* mask) @ W, bf16 out. 128 rows/block, 4 waves.
// A-frags from global x (per-lane, cvt in reg); W in swizzled LDS.
// Epilogue: transpose acc through LDS ([128][TRP] bf16, time-shared with the W
// tile) then fully-coalesced uint4 stores — the scattered 2B stores were the
// R3-R7 bottleneck (WRITE_SIZE 32MB vs 12.8 ideal; ~4 segments per wave-store).
__global__ __launch_bounds__(256, 4) void gemmcount_kernel(
        const void* eidx, const int* __restrict__ flag, int* __restrict__ deg,
        const float* __restrict__ x, const unsigned short* __restrict__ Wt,
        const int* __restrict__ mask, unsigned short* __restrict__ hb){
    __shared__ unsigned short lsd[128 * TRP];  // phase1: W [128][128]; phase2: tr [128][TRP]
    __shared__ int msk[GEMM_ROWS];
    const int t = threadIdx.x;

    if(blockIdx.x < CNT_BLOCKS){
        const int is64 = flag[0];
        for(int e = blockIdx.x * 256 + t; e < NE; e += CNT_BLOCKS * 256){
            int d = get_idx(eidx, (long long)NE + e, is64);
            atomicAdd(&deg[d], 1);
        }
        return;
    }

    const int r0 = (blockIdx.x - CNT_BLOCKS) * GEMM_ROWS;
#pragma unroll
    for(int j = 0; j < 8; ++j){              // stage Wt (swizzled): chunk kc -> kc^(n&7)
        int c = t + 256 * j;
        int n = c >> 4, kc = c & 15;
        uint4 v = *(const uint4*)&Wt[n * D + kc * 8];
        *(uint4*)&lsd[n * D + ((kc ^ (n & 7)) * 8)] = v;
    }
    if(t < GEMM_ROWS) msk[t] = (r0 + t < NN) ? mask[r0 + t] : 0;
    __syncthreads();

    const int wv = t >> 6, lane = t & 63;
    const int r15 = lane & 15, quad = lane >> 4;
    const int sw = r15 & 7;

    f32x4 acc[2][8];
#pragma unroll
    for(int g = 0; g < 2; ++g)
#pragma unroll
        for(int nf = 0; nf < 8; ++nf) acc[g][nf] = (f32x4){0.f, 0.f, 0.f, 0.f};

#pragma unroll 2
    for(int ks = 0; ks < 4; ++ks){
        const int kq = ks * 4 + quad;        // actual k-chunk (8 elems)
        bfrag a[2];
#pragma unroll
        for(int g = 0; g < 2; ++g){
            const int lrow = wv * 32 + g * 16 + r15;
            const int arow = r0 + lrow;
            bfrag av = (bfrag){0,0,0,0,0,0,0,0};
            if(arow < NN && msk[lrow]){
                float4 u = *(const float4*)&x[(size_t)arow * D + kq * 8];
                float4 v = *(const float4*)&x[(size_t)arow * D + kq * 8 + 4];
                av[0] = (short)f2bf1(u.x); av[1] = (short)f2bf1(u.y);
                av[2] = (short)f2bf1(u.z); av[3] = (short)f2bf1(u.w);
                av[4] = (short)f2bf1(v.x); av[5] = (short)f2bf1(v.y);
                av[6] = (short)f2bf1(v.z); av[7] = (short)f2bf1(v.w);
            }
            a[g] = av;
        }
        const int kc = kq ^ sw;              // swizzled position holding chunk kq
#pragma unroll
        for(int nf = 0; nf < 8; ++nf){
            bfrag b = *(const bfrag*)&lsd[(nf * 16 + r15) * D + kc * 8];
            acc[0][nf] = __builtin_amdgcn_mfma_f32_16x16x32_bf16(a[0], b, acc[0][nf], 0, 0, 0);
            acc[1][nf] = __builtin_amdgcn_mfma_f32_16x16x32_bf16(a[1], b, acc[1][nf], 0, 0, 0);
        }
    }
    __syncthreads();                          // all W reads done; lsd becomes transpose buf

    // D layout: col = lane&15, row = (lane>>4)*4 + reg  -> write [row][TRP] bf16
#pragma unroll
    for(int g = 0; g < 2; ++g)
#pragma unroll
        for(int nf = 0; nf < 8; ++nf)
#pragma unroll
            for(int j = 0; j < 4; ++j){
                int lrow = wv * 32 + g * 16 + quad * 4 + j;
                lsd[lrow * TRP + nf * 16 + r15] = f2bf1(acc[g][nf][j]);
            }
    __syncthreads();

    // coalesced store: lane-contiguous 16B chunks over the block's 32KB hb span
#pragma unroll
    for(int c = 0; c < 8; ++c){
        int gch = t + 256 * c;               // 0..2047
        int row = gch >> 4, cc = gch & 15;
        if(r0 + row < NN && msk[row]){
            uint4 v = *(const uint4*)&lsd[row * TRP + cc * 8];
            *(uint4*)&hb[(size_t)(r0 + row) * D + cc * 8] = v;
        }
    }
}

// Block-local exclusive scan of deg -> rowofs + masked dinv; the LAST finishing
// block (device-scope ticket) exclusive-scans the 98 per-block partials in place.
__global__ __launch_bounds__(1024) void scan12_kernel(const int* __restrict__ deg,
                                                      int* __restrict__ rowofs,
                                                      int* __restrict__ partials,
                                                      float* __restrict__ dinv,
                                                      const int* __restrict__ mask,
                                                      int* __restrict__ done){
    __shared__ int s[1024];
    __shared__ int amlast;
    const int tid = threadIdx.x;
    const int i = blockIdx.x * 1024 + tid;
    const int v = (i < NN) ? deg[i] : 0;
    s[tid] = v;
    __syncthreads();
    for(int off = 1; off < 1024; off <<= 1){
        int u = (tid >= off) ? s[tid - off] : 0;
        __syncthreads();
        s[tid] += u;
        __syncthreads();
    }
    if(i < NN){
        rowofs[i] = s[tid] - v;                        // block-local exclusive
        dinv[i]   = mask[i] ? rsqrtf((float)(v + 1)) : 0.f;
    }
    if(tid == 1023){
        partials[blockIdx.x] = s[tid];
        __threadfence();                               // release partials store
        int tk = atomicAdd(done, 1);
        amlast = (tk == SCAN_BLOCKS - 1);
    }
    __syncthreads();
    if(amlast){
        __threadfence();                               // acquire before reads
        int pv = (tid < SCAN_BLOCKS) ? atomicOr(&partials[tid], 0) : 0;
        s[tid] = pv;
        __syncthreads();
        for(int off = 1; off < 128; off <<= 1){
            int u = (tid >= off) ? s[tid - off] : 0;
            __syncthreads();
            s[tid] += u;
            __syncthreads();
        }
        if(tid < SCAN_BLOCKS) partials[tid] = s[tid] - pv;   // exclusive offsets
    }
}

// Scatter unmasked->unmasked edges (dinv==0 encodes masked): elist2 = {src, dinv[src]}.
__global__ __launch_bounds__(256) void scatter_kernel(const void* eidx,
                                                      const int* __restrict__ flag,
                                                      const int* __restrict__ rowofs,
                                                      const int* __restrict__ partials,
                                                      const float* __restrict__ dinv,
                                                      int* __restrict__ cursor,
                                                      int2* __restrict__ elist2){
    const int is64 = flag[0];
    for(int e = blockIdx.x * 256 + threadIdx.x; e < NE; e += gridDim.x * 256){
        int s = get_idx(eidx, e, is64);
        int d = get_idx(eidx, (long long)NE + e, is64);
        float ds = dinv[s];
        if(ds != 0.f && dinv[d] != 0.f){
            int p = atomicAdd(&cursor[d], 1);
            elist2[rowofs[d] + partials[d >> 10] + p] = make_int2(s, __float_as_int(ds));
        }
    }
}

// out[n] = m[n] * ( dinv[n]*(dinv[n]*h[n] + sum_e dinv[s]*h[s]) + bias )
// One wave = TWO nodes: lanes 0-31 node A, 32-63 node B; lane owns 4 dims.
__global__ __launch_bounds__(256) void agg_kernel(const uint2* __restrict__ hb2,
                                                  const float* __restrict__ dinv,
                                                  const int* __restrict__ rowofs,
                                                  const int* __restrict__ cursor,
                                                  const int* __restrict__ partials,
                                                  const int2* __restrict__ elist2,
                                                  const float* __restrict__ bias,
                                                  float* __restrict__ out){
    const int t = threadIdx.x;
    const int wave = t >> 6, lane = t & 63;
    const int half = lane >> 5, hl = lane & 31;
    const int n = blockIdx.x * 8 + wave * 2 + half;   // NN % 8 == 0
    const float dn = dinv[n];                          // 0 => masked node
    const int len  = cursor[n];                        // 0 for masked nodes
    const int base = rowofs[n] + partials[n >> 10];

    float4 h = bf4f4(hb2[(size_t)n * 32 + hl]);        // self-loop (x0 if masked)
    float4 a0, a1;
    a0.x = dn * h.x; a0.y = dn * h.y; a0.z = dn * h.z; a0.w = dn * h.w;
    a1 = make_float4(0.f, 0.f, 0.f, 0.f);

    const int lenmax = max(len, __shfl(len, lane ^ 32));
    for(int j0 = 0; j0 < lenmax; j0 += 32){
        int2 u = make_int2(0, 0);
        if(j0 + hl < len) u = elist2[base + j0 + hl];
        const int mm = min(32, lenmax - j0);
        int j = 0;
        for(; j + 1 < mm; j += 2){
            int   s0 = __shfl(u.x, half * 32 + j);
            int   s1 = __shfl(u.x, half * 32 + j + 1);
            float d0 = __int_as_float(__shfl(u.y, half * 32 + j));
            float d1 = __int_as_float(__shfl(u.y, half * 32 + j + 1));
            if(j0 + j < len){
                float4 hv = bf4f4(hb2[(size_t)s0 * 32 + hl]);
                a0.x += d0 * hv.x; a0.y += d0 * hv.y;
                a0.z += d0 * hv.z; a0.w += d0 * hv.w;
            }
            if(j0 + j + 1 < len){
                float4 hv = bf4f4(hb2[(size_t)s1 * 32 + hl]);
                a1.x += d1 * hv.x; a1.y += d1 * hv.y;
                a1.z += d1 * hv.z; a1.w += d1 * hv.w;
            }
        }
        if(j < mm && j0 + j < len){
            int   s0 = __shfl(u.x, half * 32 + j);
            float d0 = __int_as_float(__shfl(u.y, half * 32 + j));
            float4 hv = bf4f4(hb2[(size_t)s0 * 32 + hl]);
            a0.x += d0 * hv.x; a0.y += d0 * hv.y;
            a0.z += d0 * hv.z; a0.w += d0 * hv.w;
        }
    }
    float4 b = ((const float4*)bias)[hl];
    float4 o;
    if(dn != 0.f){
        o.x = dn * (a0.x + a1.x) + b.x;
        o.y = dn * (a0.y + a1.y) + b.y;
        o.z = dn * (a0.z + a1.z) + b.z;
        o.w = dn * (a0.w + a1.w) + b.w;
    } else {
        o = make_float4(0.f, 0.f, 0.f, 0.f);
    }
    ((float4*)out)[(size_t)n * 32 + hl] = o;
}

extern "C" void kernel_launch(void* const* d_in, const int* in_sizes, int n_in,
                              void* d_out, int out_size, void* d_ws, size_t ws_size,
                              hipStream_t stream){
    const float* x    = (const float*)d_in[0];
    const float* W    = (const float*)d_in[1];
    const float* bias = (const float*)d_in[2];
    const void*  eidx = d_in[3];
    const int*   mask = (const int*)d_in[4];
    float* out = (float*)d_out;

    char* ws = (char*)d_ws;
    int*            deg    = (int*)(ws + OFF_DEG);
    int*            rowofs = (int*)(ws + OFF_ROWOFS);
    int*            cursor = (int*)(ws + OFF_CURSOR);
    float*          dinv   = (float*)(ws + OFF_DINV);
    int*            flag   = (int*)(ws + OFF_FLAG);
    int*            part   = (int*)(ws + OFF_PART);
    unsigned short* wt     = (unsigned short*)(ws + OFF_WT);
    int2*           elist2 = (int2*)(ws + OFF_ELIST2);
    unsigned short* hb     = (unsigned short*)(ws + OFF_HBF);

    prep_kernel     <<<SCAN_BLOCKS + 64, 256, 0, stream>>>(eidx, flag, W, wt,
                                                           (int4*)deg, (int4*)cursor);
    gemmcount_kernel<<<CNT_BLOCKS + GEMM_BLOCKS, 256, 0, stream>>>(eidx, flag, deg,
                                                                   x, wt, mask, hb);
    scan12_kernel   <<<SCAN_BLOCKS, 1024, 0, stream>>>(deg, rowofs, part, dinv,
                                                       mask, flag + 4);
    scatter_kernel  <<<1024, 256, 0, stream>>>(eidx, flag, rowofs, part, dinv,
                                               cursor, elist2);
    agg_kernel      <<<NN/8, 256, 0, stream>>>((const uint2*)hb, dinv, rowofs, cursor,
                                               part, elist2, bias, out);
}